// Round 3
// baseline (1386.020 us; speedup 1.0000x reference)
//
#include <hip/hip_runtime.h>
#include <hip/hip_bf16.h>

#define N_NODES 20000
#define N_EDGES 320000
#define DIM 128
#define HEADS 3
#define LAYERS 3
#define NGRAPH 64
#define NEG_SLOPE 0.2f

typedef const __hip_bfloat16* bfp;
typedef __hip_bfloat16 bf16;

__device__ __forceinline__ float b2f(unsigned short u) {
    return __uint_as_float(((unsigned)u) << 16);
}
__device__ __forceinline__ float leaky(float z) {
    return z >= 0.f ? z : NEG_SLOPE * z;
}

// ---------------- dtype detection ----------------
// If the float inputs are actually fp32, reading them as bf16 shows random
// exponent fields in the odd halves; real bf16 data from N(0,~1) never has
// |x| >= 2^13. Count exponent>=140 over the first 64K shorts of feat.
__global__ void detect_kernel(const unsigned short* __restrict__ probe,
                              int nshorts, int* __restrict__ flag) {
    __shared__ int cnt_s;
    if (threadIdx.x == 0) cnt_s = 0;
    __syncthreads();
    int c = 0;
    for (int i = threadIdx.x; i < nshorts; i += 256) {
        int e = (probe[i] >> 7) & 0xFF;
        if (e >= 140) ++c;
    }
    atomicAdd(&cnt_s, c);
    __syncthreads();
    if (threadIdx.x == 0) *flag = (cnt_s > 8) ? 1 : 0;
}

// normalize a float tensor (fp32 or bf16 per *flag) into a bf16 ws copy
__global__ void cvt_kernel(const void* __restrict__ in, bf16* __restrict__ out,
                           int n, const int* __restrict__ flag) {
    int i = blockIdx.x * 256 + threadIdx.x;
    if (i >= n) return;
    if (*flag)
        out[i] = __float2bfloat16(((const float*)in)[i]);
    else
        out[i] = ((const bf16*)in)[i];
}

// ---------------- setup kernels ----------------

__global__ void count_kernel(const int* __restrict__ idx, int* __restrict__ cnt, int n) {
    int i = blockIdx.x * 256 + threadIdx.x;
    if (i < n) atomicAdd(&cnt[idx[i]], 1);
}

// single-block exclusive scan: ptr[0..n], ptr[n] = total
__global__ void scan_kernel(const int* __restrict__ cnt, int* __restrict__ ptr, int n) {
    __shared__ int sums[256];
    int tid = threadIdx.x;
    int chunk = (n + 255) / 256;
    int b = tid * chunk;
    int e = min(b + chunk, n);
    int loc = 0;
    for (int i = b; i < e; ++i) loc += cnt[i];
    sums[tid] = loc;
    __syncthreads();
    if (tid == 0) {
        int run = 0;
        for (int j = 0; j < 256; ++j) { int t = sums[j]; sums[j] = run; run += t; }
        ptr[n] = run;
    }
    __syncthreads();
    int run = sums[tid];
    for (int i = b; i < e; ++i) { ptr[i] = run; run += cnt[i]; }
}

__global__ void fill_kernel(const int* __restrict__ src, const int* __restrict__ dst,
                            const int* __restrict__ rp, int* __restrict__ cursor,
                            int* __restrict__ esrc) {
    int e = blockIdx.x * 256 + threadIdx.x;
    if (e < N_EDGES) {
        int d = dst[e];
        int pos = atomicAdd(&cursor[d], 1);
        esrc[rp[d] + pos] = src[e];
    }
}

__global__ void sentinel_kernel(bf16* out, int n) {
    int i = blockIdx.x * 256 + threadIdx.x;
    if (i < n) out[i] = __float2bfloat16(2.0f);
}

// ---------------- GEMM: C[M,N] = A[M,K] (bf16) * B[N,K]^T (bf16), fp32 acc ----
__global__ __launch_bounds__(256) void gemm_nt(
    const bf16* __restrict__ A, const bf16* __restrict__ B,
    bf16* __restrict__ C, int M, int N, int K,
    const bf16* __restrict__ bias, const bf16* __restrict__ resid,
    int do_relu)
{
    constexpr int BM = 64, BN = 64, BK = 32, PAD = 4;
    __shared__ float As[BK][BM + PAD];
    __shared__ float Bs[BK][BN + PAD];
    const int tid = threadIdx.x;
    const int m0 = blockIdx.x * BM;
    const int n0 = blockIdx.y * BN;
    const int tr = tid >> 4, tc = tid & 15;
    const int lr = tid >> 2;          // 0..63 tile row
    const int lk = (tid & 3) * 8;     // 0,8,16,24 k-chunk
    float acc[4][4] = {};

    for (int k0 = 0; k0 < K; k0 += BK) {
        {
            int gm = m0 + lr;
            float va[8] = {0, 0, 0, 0, 0, 0, 0, 0};
            if (gm < M) {
                float4 raw = *((const float4*)(A + (size_t)gm * K + (k0 + lk)));
                const unsigned short* u = (const unsigned short*)&raw;
#pragma unroll
                for (int j = 0; j < 8; ++j) va[j] = b2f(u[j]);
            }
#pragma unroll
            for (int j = 0; j < 8; ++j) As[lk + j][lr] = va[j];
        }
        {
            float4 raw = *((const float4*)(B + (size_t)(n0 + lr) * K + (k0 + lk)));
            const unsigned short* u = (const unsigned short*)&raw;
#pragma unroll
            for (int j = 0; j < 8; ++j) Bs[lk + j][lr] = b2f(u[j]);
        }
        __syncthreads();
#pragma unroll
        for (int k = 0; k < BK; ++k) {
            float4 av = *((const float4*)&As[k][tr * 4]);
            float4 bv = *((const float4*)&Bs[k][tc * 4]);
            acc[0][0] += av.x * bv.x; acc[0][1] += av.x * bv.y;
            acc[0][2] += av.x * bv.z; acc[0][3] += av.x * bv.w;
            acc[1][0] += av.y * bv.x; acc[1][1] += av.y * bv.y;
            acc[1][2] += av.y * bv.z; acc[1][3] += av.y * bv.w;
            acc[2][0] += av.z * bv.x; acc[2][1] += av.z * bv.y;
            acc[2][2] += av.z * bv.z; acc[2][3] += av.z * bv.w;
            acc[3][0] += av.w * bv.x; acc[3][1] += av.w * bv.y;
            acc[3][2] += av.w * bv.z; acc[3][3] += av.w * bv.w;
        }
        __syncthreads();
    }

    const int cn = n0 + tc * 4;
    float bb[4] = {0, 0, 0, 0};
    if (bias) {
#pragma unroll
        for (int j = 0; j < 4; ++j) bb[j] = __bfloat162float(bias[cn + j]);
    }
#pragma unroll
    for (int i = 0; i < 4; ++i) {
        int m = m0 + tr * 4 + i;
        if (m >= M) continue;
        float v[4];
#pragma unroll
        for (int j = 0; j < 4; ++j) v[j] = acc[i][j];
        if (bias) {
#pragma unroll
            for (int j = 0; j < 4; ++j) {
                v[j] += bb[j];
                if (do_relu) v[j] = fmaxf(v[j], 0.f);
                v[j] += __bfloat162float(resid[(size_t)m * N + cn + j]);
            }
        }
        ushort4 pk;
        bf16 o0 = __float2bfloat16(v[0]);
        bf16 o1 = __float2bfloat16(v[1]);
        bf16 o2 = __float2bfloat16(v[2]);
        bf16 o3 = __float2bfloat16(v[3]);
        pk.x = *(unsigned short*)&o0;
        pk.y = *(unsigned short*)&o1;
        pk.z = *(unsigned short*)&o2;
        pk.w = *(unsigned short*)&o3;
        *((ushort4*)(C + (size_t)m * N + cn)) = pk;
    }
}

// ---------------- attention scores: one wave per (node, head) ----------------
__global__ __launch_bounds__(256) void scores_kernel(
    const bf16* __restrict__ h, const bf16* __restrict__ a_ns,
    const bf16* __restrict__ a_nd,
    float* __restrict__ s_ns, float* __restrict__ s_nd)
{
    int wid = blockIdx.x * 4 + (threadIdx.x >> 6);
    if (wid >= N_NODES * HEADS) return;
    int lane = threadIdx.x & 63;
    int n = wid / HEADS, hh = wid - n * HEADS;
    const bf16* hp = h + (size_t)n * (HEADS * DIM) + hh * DIM;
    float v0 = __bfloat162float(hp[lane]);
    float v1 = __bfloat162float(hp[lane + 64]);
    float pns = v0 * __bfloat162float(a_ns[hh * DIM + lane]) +
                v1 * __bfloat162float(a_ns[hh * DIM + lane + 64]);
    float pnd = v0 * __bfloat162float(a_nd[hh * DIM + lane]) +
                v1 * __bfloat162float(a_nd[hh * DIM + lane + 64]);
    for (int o = 32; o > 0; o >>= 1) {
        pns += __shfl_down(pns, o);
        pnd += __shfl_down(pnd, o);
    }
    if (lane == 0) { s_ns[wid] = pns; s_nd[wid] = pnd; }
}

// ---------------- per-dst softmax + aggregate (CSR, no atomics) ----------------
__global__ __launch_bounds__(128) void agg_kernel(
    const bf16* __restrict__ h, const int* __restrict__ rp,
    const int* __restrict__ esrc, const float* __restrict__ s_ns,
    const float* __restrict__ s_nd, bf16* __restrict__ agg)
{
    const int node = blockIdx.x;
    const int tid = threadIdx.x;
    const int beg = rp[node], end = rp[node + 1];
    const int cnt = end - beg;
    bf16* outp = agg + (size_t)node * (HEADS * DIM);
    const bf16 z = __float2bfloat16(0.f);
    if (cnt <= 0) {
        outp[tid] = z; outp[tid + 128] = z; outp[tid + 256] = z;
        return;
    }
    const float snd0 = s_nd[node * 3 + 0];
    const float snd1 = s_nd[node * 3 + 1];
    const float snd2 = s_nd[node * 3 + 2];
    __shared__ float red[2][3];
    float m0 = -1e30f, m1 = -1e30f, m2 = -1e30f;
    for (int i = tid; i < cnt; i += 128) {
        int s = esrc[beg + i];
        m0 = fmaxf(m0, leaky(s_ns[s * 3 + 0] + snd0));
        m1 = fmaxf(m1, leaky(s_ns[s * 3 + 1] + snd1));
        m2 = fmaxf(m2, leaky(s_ns[s * 3 + 2] + snd2));
    }
    for (int o = 32; o > 0; o >>= 1) {
        m0 = fmaxf(m0, __shfl_down(m0, o));
        m1 = fmaxf(m1, __shfl_down(m1, o));
        m2 = fmaxf(m2, __shfl_down(m2, o));
    }
    if ((tid & 63) == 0) {
        int w = tid >> 6;
        red[w][0] = m0; red[w][1] = m1; red[w][2] = m2;
    }
    __syncthreads();
    m0 = fmaxf(red[0][0], red[1][0]);
    m1 = fmaxf(red[0][1], red[1][1]);
    m2 = fmaxf(red[0][2], red[1][2]);
    __syncthreads();
    float ss0 = 0.f, ss1 = 0.f, ss2 = 0.f;
    for (int i = tid; i < cnt; i += 128) {
        int s = esrc[beg + i];
        ss0 += __expf(leaky(s_ns[s * 3 + 0] + snd0) - m0);
        ss1 += __expf(leaky(s_ns[s * 3 + 1] + snd1) - m1);
        ss2 += __expf(leaky(s_ns[s * 3 + 2] + snd2) - m2);
    }
    for (int o = 32; o > 0; o >>= 1) {
        ss0 += __shfl_down(ss0, o);
        ss1 += __shfl_down(ss1, o);
        ss2 += __shfl_down(ss2, o);
    }
    if ((tid & 63) == 0) {
        int w = tid >> 6;
        red[w][0] = ss0; red[w][1] = ss1; red[w][2] = ss2;
    }
    __syncthreads();
    ss0 = red[0][0] + red[1][0];
    ss1 = red[0][1] + red[1][1];
    ss2 = red[0][2] + red[1][2];
    __shared__ float pch[64][3];
    __shared__ int sch[64];
    float a0 = 0.f, a1 = 0.f, a2 = 0.f;
    for (int c0 = 0; c0 < cnt; c0 += 64) {
        int ce = min(64, cnt - c0);
        __syncthreads();
        if (tid < ce) {
            int s = esrc[beg + c0 + tid];
            sch[tid] = s;
            pch[tid][0] = __expf(leaky(s_ns[s * 3 + 0] + snd0) - m0);
            pch[tid][1] = __expf(leaky(s_ns[s * 3 + 1] + snd1) - m1);
            pch[tid][2] = __expf(leaky(s_ns[s * 3 + 2] + snd2) - m2);
        }
        __syncthreads();
        for (int j = 0; j < ce; ++j) {
            const bf16* hp = h + (size_t)sch[j] * (HEADS * DIM) + tid;
            a0 += pch[j][0] * __bfloat162float(hp[0]);
            a1 += pch[j][1] * __bfloat162float(hp[128]);
            a2 += pch[j][2] * __bfloat162float(hp[256]);
        }
    }
    outp[tid]       = __float2bfloat16(a0 / ss0);
    outp[tid + 128] = __float2bfloat16(a1 / ss1);
    outp[tid + 256] = __float2bfloat16(a2 / ss2);
}

// ---------------- gate MLP: one block (256 thr) per node ----------------
__global__ __launch_bounds__(256) void gate_kernel(
    const bf16* __restrict__ feat, const bf16* __restrict__ p1w,
    const bf16* __restrict__ p1b, const bf16* __restrict__ p2w,
    const bf16* __restrict__ p2b, float* __restrict__ gate)
{
    const int n = blockIdx.x, tid = threadIdx.x;
    __shared__ float f[DIM];
    __shared__ float red[4];
    if (tid < DIM) f[tid] = __bfloat162float(feat[(size_t)n * DIM + tid]);
    __syncthreads();
    const bf16* wrow = p1w + (size_t)tid * DIM;
    float acc = 0.f;
#pragma unroll
    for (int k = 0; k < DIM; k += 8) {
        float4 raw = *((const float4*)(wrow + k));
        const unsigned short* u = (const unsigned short*)&raw;
        acc += b2f(u[0]) * f[k]     + b2f(u[1]) * f[k + 1] +
               b2f(u[2]) * f[k + 2] + b2f(u[3]) * f[k + 3] +
               b2f(u[4]) * f[k + 4] + b2f(u[5]) * f[k + 5] +
               b2f(u[6]) * f[k + 6] + b2f(u[7]) * f[k + 7];
    }
    float t = fmaxf(acc + __bfloat162float(p1b[tid]), 0.f) * __bfloat162float(p2w[tid]);
    for (int o = 32; o > 0; o >>= 1) t += __shfl_down(t, o);
    if ((tid & 63) == 0) red[tid >> 6] = t;
    __syncthreads();
    if (tid == 0)
        gate[n] = red[0] + red[1] + red[2] + red[3] + __bfloat162float(p2b[0]);
}

// ---------------- per-graph softmax pooling: one block per graph ----------------
__global__ __launch_bounds__(128) void pool_kernel(
    const bf16* __restrict__ feat, const float* __restrict__ gate,
    const int* __restrict__ gptr, float* __restrict__ out_acc)
{
    const int g = blockIdx.x, tid = threadIdx.x;
    const int beg = gptr[g], end = gptr[g + 1];
    if (beg >= end) return;
    __shared__ float red[2];
    float m = -1e30f;
    for (int i = beg + tid; i < end; i += 128) m = fmaxf(m, gate[i]);
    for (int o = 32; o > 0; o >>= 1) m = fmaxf(m, __shfl_down(m, o));
    if ((tid & 63) == 0) red[tid >> 6] = m;
    __syncthreads();
    m = fmaxf(red[0], red[1]);
    __syncthreads();
    float s = 0.f;
    for (int i = beg + tid; i < end; i += 128) s += __expf(gate[i] - m);
    for (int o = 32; o > 0; o >>= 1) s += __shfl_down(s, o);
    if ((tid & 63) == 0) red[tid >> 6] = s;
    __syncthreads();
    s = red[0] + red[1];
    float acc = 0.f;
    for (int i = beg; i < end; ++i)
        acc += __expf(gate[i] - m) * __bfloat162float(feat[(size_t)i * DIM + tid]);
    out_acc[g * DIM + tid] += acc / s;
}

// dtype-dispatching writeout: fp32 or bf16 depending on detected input dtype
__global__ void writeout_kernel(const float* __restrict__ out_acc,
                                void* __restrict__ out, const int* __restrict__ flag) {
    int i = blockIdx.x * 256 + threadIdx.x;
    if (i < NGRAPH * DIM) {
        float v = out_acc[i] * (1.f / 3.f);
        if (*flag) ((float*)out)[i] = v;
        else ((bf16*)out)[i] = __float2bfloat16(v);
    }
}

// ---------------- host launcher ----------------
extern "C" void kernel_launch(void* const* d_in, const int* in_sizes, int n_in,
                              void* d_out, int out_size, void* d_ws, size_t ws_size,
                              hipStream_t stream)
{
    const void* feat_in = d_in[0];
    const int* src = (const int*)d_in[1];
    const int* dst = (const int*)d_in[2];
    const int* gid = (const int*)d_in[3];

    char* base = (char*)d_ws;
    size_t off = 0;
    auto carve = [&](size_t bytes) -> void* {
        void* p = base + off;
        off = (off + bytes + 255) & ~(size_t)255;
        return p;
    };
    // small / index arrays first
    int* dflag  = (int*)carve(sizeof(int));
    int* deg    = (int*)carve(sizeof(int) * N_NODES);
    int* cursor = (int*)carve(sizeof(int) * N_NODES);
    int* rp     = (int*)carve(sizeof(int) * (N_NODES + 1));
    int* gcnt   = (int*)carve(sizeof(int) * NGRAPH);
    int* gptr   = (int*)carve(sizeof(int) * (NGRAPH + 1));
    int* esrc   = (int*)carve(sizeof(int) * N_EDGES);
    float* s_ns = (float*)carve(sizeof(float) * N_NODES * HEADS);
    float* s_nd = (float*)carve(sizeof(float) * N_NODES * HEADS);
    float* gateb = (float*)carve(sizeof(float) * N_NODES);
    float* out_acc = (float*)carve(sizeof(float) * NGRAPH * DIM);
    // normalized bf16 copies of all float inputs
    bf16* featA = (bf16*)carve(sizeof(bf16) * N_NODES * DIM);
    bf16* featB = (bf16*)carve(sizeof(bf16) * N_NODES * DIM);
    bf16* cfc   = (bf16*)carve(sizeof(bf16) * LAYERS * HEADS * DIM * DIM);
    bf16* cans  = (bf16*)carve(sizeof(bf16) * LAYERS * HEADS * DIM);
    bf16* cand  = (bf16*)carve(sizeof(bf16) * LAYERS * HEADS * DIM);
    bf16* ctw   = (bf16*)carve(sizeof(bf16) * LAYERS * DIM * HEADS * DIM);
    bf16* ctb   = (bf16*)carve(sizeof(bf16) * LAYERS * DIM);
    bf16* cp1w  = (bf16*)carve(sizeof(bf16) * LAYERS * 2 * DIM * DIM);
    bf16* cp1b  = (bf16*)carve(sizeof(bf16) * LAYERS * 2 * DIM);
    bf16* cp2w  = (bf16*)carve(sizeof(bf16) * LAYERS * 2 * DIM);
    bf16* cp2b  = (bf16*)carve(sizeof(bf16) * LAYERS);
    // big bf16 intermediates
    bf16* hbuf   = (bf16*)carve(sizeof(bf16) * N_NODES * HEADS * DIM);
    bf16* aggbuf = (bf16*)carve(sizeof(bf16) * N_NODES * HEADS * DIM);

    if (off > ws_size) {
        sentinel_kernel<<<(out_size + 255) / 256, 256, 0, stream>>>(
            (bf16*)d_out, out_size);
        return;
    }

    // detect input dtype from feat (works for either storage)
    detect_kernel<<<1, 256, 0, stream>>>((const unsigned short*)feat_in, 65536, dflag);

    // normalize all float inputs to bf16 ws copies
    auto cvt = [&](const void* in, bf16* out, int n) {
        cvt_kernel<<<(n + 255) / 256, 256, 0, stream>>>(in, out, n, dflag);
    };
    cvt(d_in[0],  featA, N_NODES * DIM);
    cvt(d_in[4],  cfc,  LAYERS * HEADS * DIM * DIM);
    cvt(d_in[5],  cans, LAYERS * HEADS * DIM);
    cvt(d_in[6],  cand, LAYERS * HEADS * DIM);
    cvt(d_in[7],  ctw,  LAYERS * DIM * HEADS * DIM);
    cvt(d_in[8],  ctb,  LAYERS * DIM);
    cvt(d_in[9],  cp1w, LAYERS * 2 * DIM * DIM);
    cvt(d_in[10], cp1b, LAYERS * 2 * DIM);
    cvt(d_in[11], cp2w, LAYERS * 2 * DIM);
    cvt(d_in[12], cp2b, LAYERS);

    hipMemsetAsync(deg, 0, sizeof(int) * N_NODES, stream);
    hipMemsetAsync(cursor, 0, sizeof(int) * N_NODES, stream);
    hipMemsetAsync(gcnt, 0, sizeof(int) * NGRAPH, stream);
    hipMemsetAsync(out_acc, 0, sizeof(float) * NGRAPH * DIM, stream);

    count_kernel<<<(N_EDGES + 255) / 256, 256, 0, stream>>>(dst, deg, N_EDGES);
    count_kernel<<<(N_NODES + 255) / 256, 256, 0, stream>>>(gid, gcnt, N_NODES);
    scan_kernel<<<1, 256, 0, stream>>>(deg, rp, N_NODES);
    scan_kernel<<<1, 256, 0, stream>>>(gcnt, gptr, NGRAPH);
    fill_kernel<<<(N_EDGES + 255) / 256, 256, 0, stream>>>(src, dst, rp, cursor, esrc);

    bf16* fin = featA;
    bf16* fout = featB;
    for (int d = 0; d < LAYERS; ++d) {
        gemm_nt<<<dim3(313, 6), 256, 0, stream>>>(
            fin, cfc + (size_t)d * HEADS * DIM * DIM, hbuf,
            N_NODES, HEADS * DIM, DIM, nullptr, nullptr, 0);
        scores_kernel<<<(N_NODES * HEADS + 3) / 4, 256, 0, stream>>>(
            hbuf, cans + (size_t)d * HEADS * DIM, cand + (size_t)d * HEADS * DIM,
            s_ns, s_nd);
        agg_kernel<<<N_NODES, 128, 0, stream>>>(hbuf, rp, esrc, s_ns, s_nd, aggbuf);
        gemm_nt<<<dim3(313, 2), 256, 0, stream>>>(
            aggbuf, ctw + (size_t)d * DIM * HEADS * DIM, fout,
            N_NODES, DIM, HEADS * DIM, ctb + (size_t)d * DIM, fin,
            (d < LAYERS - 1) ? 1 : 0);
        gate_kernel<<<N_NODES, 256, 0, stream>>>(
            fout, cp1w + (size_t)d * 2 * DIM * DIM, cp1b + (size_t)d * 2 * DIM,
            cp2w + (size_t)d * 2 * DIM, cp2b + d, gateb);
        pool_kernel<<<NGRAPH, 128, 0, stream>>>(fout, gateb, gptr, out_acc);
        bf16* t = fin; fin = fout; fout = t;
    }
    writeout_kernel<<<(NGRAPH * DIM + 255) / 256, 256, 0, stream>>>(
        out_acc, d_out, dflag);
}

// Round 4
// 910.313 us; speedup vs baseline: 1.5226x; 1.5226x over previous
//
#include <hip/hip_runtime.h>
#include <hip/hip_bf16.h>

#define N_NODES 20000
#define N_EDGES 320000
#define DIM 128
#define HEADS 3
#define LAYERS 3
#define NGRAPH 64
#define NEG_SLOPE 0.2f

typedef const __hip_bfloat16* bfp;
typedef __hip_bfloat16 bf16;
typedef short v8s __attribute__((ext_vector_type(8)));
typedef float v4f __attribute__((ext_vector_type(4)));

__device__ __forceinline__ float b2f(unsigned short u) {
    return __uint_as_float(((unsigned)u) << 16);
}
__device__ __forceinline__ float leaky(float z) {
    return z >= 0.f ? z : NEG_SLOPE * z;
}

// ---------------- dtype detection (fp32 vs bf16 storage) ----------------
__global__ void detect_kernel(const unsigned short* __restrict__ probe,
                              int nshorts, int* __restrict__ flag) {
    __shared__ int cnt_s;
    if (threadIdx.x == 0) cnt_s = 0;
    __syncthreads();
    int c = 0;
    for (int i = threadIdx.x; i < nshorts; i += 256) {
        int e = (probe[i] >> 7) & 0xFF;
        if (e >= 140) ++c;
    }
    atomicAdd(&cnt_s, c);
    __syncthreads();
    if (threadIdx.x == 0) *flag = (cnt_s > 8) ? 1 : 0;
}

__global__ void cvt_kernel(const void* __restrict__ in, bf16* __restrict__ out,
                           int n, const int* __restrict__ flag) {
    int i = blockIdx.x * 256 + threadIdx.x;
    if (i >= n) return;
    if (*flag)
        out[i] = __float2bfloat16(((const float*)in)[i]);
    else
        out[i] = ((const bf16*)in)[i];
}

// ---------------- setup kernels ----------------

__global__ void count_kernel(const int* __restrict__ idx, int* __restrict__ cnt, int n) {
    int i = blockIdx.x * 256 + threadIdx.x;
    if (i < n) atomicAdd(&cnt[idx[i]], 1);
}

__global__ void scan_kernel(const int* __restrict__ cnt, int* __restrict__ ptr, int n) {
    __shared__ int sums[256];
    int tid = threadIdx.x;
    int chunk = (n + 255) / 256;
    int b = tid * chunk;
    int e = min(b + chunk, n);
    int loc = 0;
    for (int i = b; i < e; ++i) loc += cnt[i];
    sums[tid] = loc;
    __syncthreads();
    if (tid == 0) {
        int run = 0;
        for (int j = 0; j < 256; ++j) { int t = sums[j]; sums[j] = run; run += t; }
        ptr[n] = run;
    }
    __syncthreads();
    int run = sums[tid];
    for (int i = b; i < e; ++i) { ptr[i] = run; run += cnt[i]; }
}

__global__ void fill_kernel(const int* __restrict__ src, const int* __restrict__ dst,
                            const int* __restrict__ rp, int* __restrict__ cursor,
                            int* __restrict__ esrc) {
    int e = blockIdx.x * 256 + threadIdx.x;
    if (e < N_EDGES) {
        int d = dst[e];
        int pos = atomicAdd(&cursor[d], 1);
        esrc[rp[d] + pos] = src[e];
    }
}

__global__ void sentinel_kernel(bf16* out, int n) {
    int i = blockIdx.x * 256 + threadIdx.x;
    if (i < n) out[i] = __float2bfloat16(2.0f);
}

// ---------------- MFMA GEMM: C[M,N] = A[M,K] * B[N,K]^T (all bf16, fp32 acc) ----
// block = 4 waves; wave w computes rows [bx*64+w*16, +16) x cols [by*64, +64).
// Fragments loaded directly from global (B is L1/L2 resident at these sizes).
// Epilogue: +bias[n] (if bias), relu (if do_relu), +resid[m,n] (if resid).
__global__ __launch_bounds__(256) void gemm_mfma(
    const bf16* __restrict__ A, const bf16* __restrict__ B,
    bf16* __restrict__ C, int M, int N, int K,
    const bf16* __restrict__ bias, const bf16* __restrict__ resid,
    int do_relu)
{
    const int wave = threadIdx.x >> 6;
    const int lane = threadIdx.x & 63;
    const int quad = lane >> 4;
    const int r16  = lane & 15;
    const int m0 = blockIdx.x * 64 + wave * 16;
    const int n0 = blockIdx.y * 64;
    const int mrow = m0 + r16;
    const bool mvalid = mrow < M;
    const short* As = (const short*)A;
    const short* Bs = (const short*)B;

    v4f acc0 = {0.f, 0.f, 0.f, 0.f};
    v4f acc1 = acc0, acc2 = acc0, acc3 = acc0;

    for (int k0 = 0; k0 < K; k0 += 32) {
        v8s a = {0, 0, 0, 0, 0, 0, 0, 0};
        if (mvalid)
            a = *(const v8s*)(As + (size_t)mrow * K + k0 + quad * 8);
        const short* bp = Bs + (size_t)(n0 + r16) * K + k0 + quad * 8;
        v8s b0 = *(const v8s*)(bp);
        v8s b1 = *(const v8s*)(bp + (size_t)16 * K);
        v8s b2 = *(const v8s*)(bp + (size_t)32 * K);
        v8s b3 = *(const v8s*)(bp + (size_t)48 * K);
        acc0 = __builtin_amdgcn_mfma_f32_16x16x32_bf16(a, b0, acc0, 0, 0, 0);
        acc1 = __builtin_amdgcn_mfma_f32_16x16x32_bf16(a, b1, acc1, 0, 0, 0);
        acc2 = __builtin_amdgcn_mfma_f32_16x16x32_bf16(a, b2, acc2, 0, 0, 0);
        acc3 = __builtin_amdgcn_mfma_f32_16x16x32_bf16(a, b3, acc3, 0, 0, 0);
    }

    v4f accs[4] = {acc0, acc1, acc2, acc3};
#pragma unroll
    for (int t = 0; t < 4; ++t) {
        const int n = n0 + t * 16 + r16;   // C/D: col = lane&15
        float bb = bias ? __bfloat162float(bias[n]) : 0.f;
#pragma unroll
        for (int reg = 0; reg < 4; ++reg) {
            const int m = m0 + quad * 4 + reg;  // C/D: row = quad*4 + reg
            if (m >= M) continue;
            float v = accs[t][reg];
            if (bias) {
                v += bb;
                if (do_relu) v = fmaxf(v, 0.f);
            }
            if (resid) v += __bfloat162float(resid[(size_t)m * N + n]);
            C[(size_t)m * N + n] = __float2bfloat16(v);
        }
    }
}

// ---------------- attention scores: one wave per (node, head) ----------------
__global__ __launch_bounds__(256) void scores_kernel(
    const bf16* __restrict__ h, const bf16* __restrict__ a_ns,
    const bf16* __restrict__ a_nd,
    float* __restrict__ s_ns, float* __restrict__ s_nd)
{
    int wid = blockIdx.x * 4 + (threadIdx.x >> 6);
    if (wid >= N_NODES * HEADS) return;
    int lane = threadIdx.x & 63;
    int n = wid / HEADS, hh = wid - n * HEADS;
    const bf16* hp = h + (size_t)n * (HEADS * DIM) + hh * DIM;
    float v0 = __bfloat162float(hp[lane]);
    float v1 = __bfloat162float(hp[lane + 64]);
    float pns = v0 * __bfloat162float(a_ns[hh * DIM + lane]) +
                v1 * __bfloat162float(a_ns[hh * DIM + lane + 64]);
    float pnd = v0 * __bfloat162float(a_nd[hh * DIM + lane]) +
                v1 * __bfloat162float(a_nd[hh * DIM + lane + 64]);
    for (int o = 32; o > 0; o >>= 1) {
        pns += __shfl_down(pns, o);
        pnd += __shfl_down(pnd, o);
    }
    if (lane == 0) { s_ns[wid] = pns; s_nd[wid] = pnd; }
}

// ---------------- per-dst softmax + aggregate (CSR, no atomics) ----------------
__global__ __launch_bounds__(128) void agg_kernel(
    const bf16* __restrict__ h, const int* __restrict__ rp,
    const int* __restrict__ esrc, const float* __restrict__ s_ns,
    const float* __restrict__ s_nd, bf16* __restrict__ agg)
{
    const int node = blockIdx.x;
    const int tid = threadIdx.x;
    const int beg = rp[node], end = rp[node + 1];
    const int cnt = end - beg;
    bf16* outp = agg + (size_t)node * (HEADS * DIM);
    const bf16 z = __float2bfloat16(0.f);
    if (cnt <= 0) {
        outp[tid] = z; outp[tid + 128] = z; outp[tid + 256] = z;
        return;
    }
    const float snd0 = s_nd[node * 3 + 0];
    const float snd1 = s_nd[node * 3 + 1];
    const float snd2 = s_nd[node * 3 + 2];
    __shared__ float red[2][3];
    float m0 = -1e30f, m1 = -1e30f, m2 = -1e30f;
    for (int i = tid; i < cnt; i += 128) {
        int s = esrc[beg + i];
        m0 = fmaxf(m0, leaky(s_ns[s * 3 + 0] + snd0));
        m1 = fmaxf(m1, leaky(s_ns[s * 3 + 1] + snd1));
        m2 = fmaxf(m2, leaky(s_ns[s * 3 + 2] + snd2));
    }
    for (int o = 32; o > 0; o >>= 1) {
        m0 = fmaxf(m0, __shfl_down(m0, o));
        m1 = fmaxf(m1, __shfl_down(m1, o));
        m2 = fmaxf(m2, __shfl_down(m2, o));
    }
    if ((tid & 63) == 0) {
        int w = tid >> 6;
        red[w][0] = m0; red[w][1] = m1; red[w][2] = m2;
    }
    __syncthreads();
    m0 = fmaxf(red[0][0], red[1][0]);
    m1 = fmaxf(red[0][1], red[1][1]);
    m2 = fmaxf(red[0][2], red[1][2]);
    __syncthreads();
    float ss0 = 0.f, ss1 = 0.f, ss2 = 0.f;
    for (int i = tid; i < cnt; i += 128) {
        int s = esrc[beg + i];
        ss0 += __expf(leaky(s_ns[s * 3 + 0] + snd0) - m0);
        ss1 += __expf(leaky(s_ns[s * 3 + 1] + snd1) - m1);
        ss2 += __expf(leaky(s_ns[s * 3 + 2] + snd2) - m2);
    }
    for (int o = 32; o > 0; o >>= 1) {
        ss0 += __shfl_down(ss0, o);
        ss1 += __shfl_down(ss1, o);
        ss2 += __shfl_down(ss2, o);
    }
    if ((tid & 63) == 0) {
        int w = tid >> 6;
        red[w][0] = ss0; red[w][1] = ss1; red[w][2] = ss2;
    }
    __syncthreads();
    ss0 = red[0][0] + red[1][0];
    ss1 = red[0][1] + red[1][1];
    ss2 = red[0][2] + red[1][2];
    __shared__ float pch[64][3];
    __shared__ int sch[64];
    float a0 = 0.f, a1 = 0.f, a2 = 0.f;
    for (int c0 = 0; c0 < cnt; c0 += 64) {
        int ce = min(64, cnt - c0);
        __syncthreads();
        if (tid < ce) {
            int s = esrc[beg + c0 + tid];
            sch[tid] = s;
            pch[tid][0] = __expf(leaky(s_ns[s * 3 + 0] + snd0) - m0);
            pch[tid][1] = __expf(leaky(s_ns[s * 3 + 1] + snd1) - m1);
            pch[tid][2] = __expf(leaky(s_ns[s * 3 + 2] + snd2) - m2);
        }
        __syncthreads();
        for (int j = 0; j < ce; ++j) {
            const bf16* hp = h + (size_t)sch[j] * (HEADS * DIM) + tid;
            a0 += pch[j][0] * __bfloat162float(hp[0]);
            a1 += pch[j][1] * __bfloat162float(hp[128]);
            a2 += pch[j][2] * __bfloat162float(hp[256]);
        }
    }
    outp[tid]       = __float2bfloat16(a0 / ss0);
    outp[tid + 128] = __float2bfloat16(a1 / ss1);
    outp[tid + 256] = __float2bfloat16(a2 / ss2);
}

// ---------------- gate second layer: one wave per node ----------------
// gate[n] = sum_k h1[n,k] * p2w[k] + p2b   (h1 = relu'd hidden, 256 wide)
__global__ __launch_bounds__(256) void gate_dot(
    const bf16* __restrict__ h1, const bf16* __restrict__ p2w,
    const bf16* __restrict__ p2b, float* __restrict__ gate)
{
    int node = blockIdx.x * 4 + (threadIdx.x >> 6);
    if (node >= N_NODES) return;
    int lane = threadIdx.x & 63;
    const unsigned short* hp = (const unsigned short*)(h1 + (size_t)node * 256);
    const unsigned short* wp = (const unsigned short*)p2w;
    ushort4 hv = *(const ushort4*)(hp + lane * 4);
    ushort4 wv = *(const ushort4*)(wp + lane * 4);
    float acc = b2f(hv.x) * b2f(wv.x) + b2f(hv.y) * b2f(wv.y) +
                b2f(hv.z) * b2f(wv.z) + b2f(hv.w) * b2f(wv.w);
    for (int o = 32; o > 0; o >>= 1) acc += __shfl_down(acc, o);
    if (lane == 0) gate[node] = acc + __bfloat162float(p2b[0]);
}

// ---------------- per-graph softmax pooling: one block per graph ----------------
__global__ __launch_bounds__(128) void pool_kernel(
    const bf16* __restrict__ feat, const float* __restrict__ gate,
    const int* __restrict__ gptr, float* __restrict__ out_acc)
{
    const int g = blockIdx.x, tid = threadIdx.x;
    const int beg = gptr[g], end = gptr[g + 1];
    if (beg >= end) return;
    __shared__ float red[2];
    float m = -1e30f;
    for (int i = beg + tid; i < end; i += 128) m = fmaxf(m, gate[i]);
    for (int o = 32; o > 0; o >>= 1) m = fmaxf(m, __shfl_down(m, o));
    if ((tid & 63) == 0) red[tid >> 6] = m;
    __syncthreads();
    m = fmaxf(red[0], red[1]);
    __syncthreads();
    float s = 0.f;
    for (int i = beg + tid; i < end; i += 128) s += __expf(gate[i] - m);
    for (int o = 32; o > 0; o >>= 1) s += __shfl_down(s, o);
    if ((tid & 63) == 0) red[tid >> 6] = s;
    __syncthreads();
    s = red[0] + red[1];
    float acc = 0.f;
    for (int i = beg; i < end; ++i)
        acc += __expf(gate[i] - m) * __bfloat162float(feat[(size_t)i * DIM + tid]);
    out_acc[g * DIM + tid] += acc / s;
}

__global__ void writeout_kernel(const float* __restrict__ out_acc,
                                void* __restrict__ out, const int* __restrict__ flag) {
    int i = blockIdx.x * 256 + threadIdx.x;
    if (i < NGRAPH * DIM) {
        float v = out_acc[i] * (1.f / 3.f);
        if (*flag) ((float*)out)[i] = v;
        else ((bf16*)out)[i] = __float2bfloat16(v);
    }
}

// ---------------- host launcher ----------------
extern "C" void kernel_launch(void* const* d_in, const int* in_sizes, int n_in,
                              void* d_out, int out_size, void* d_ws, size_t ws_size,
                              hipStream_t stream)
{
    const void* feat_in = d_in[0];
    const int* src = (const int*)d_in[1];
    const int* dst = (const int*)d_in[2];
    const int* gid = (const int*)d_in[3];

    char* base = (char*)d_ws;
    size_t off = 0;
    auto carve = [&](size_t bytes) -> void* {
        void* p = base + off;
        off = (off + bytes + 255) & ~(size_t)255;
        return p;
    };
    int* dflag  = (int*)carve(sizeof(int));
    int* deg    = (int*)carve(sizeof(int) * N_NODES);
    int* cursor = (int*)carve(sizeof(int) * N_NODES);
    int* rp     = (int*)carve(sizeof(int) * (N_NODES + 1));
    int* gcnt   = (int*)carve(sizeof(int) * NGRAPH);
    int* gptr   = (int*)carve(sizeof(int) * (NGRAPH + 1));
    int* esrc   = (int*)carve(sizeof(int) * N_EDGES);
    float* s_ns = (float*)carve(sizeof(float) * N_NODES * HEADS);
    float* s_nd = (float*)carve(sizeof(float) * N_NODES * HEADS);
    float* gateb = (float*)carve(sizeof(float) * N_NODES);
    float* out_acc = (float*)carve(sizeof(float) * NGRAPH * DIM);
    bf16* featA = (bf16*)carve(sizeof(bf16) * N_NODES * DIM);
    bf16* featB = (bf16*)carve(sizeof(bf16) * N_NODES * DIM);
    bf16* cfc   = (bf16*)carve(sizeof(bf16) * LAYERS * HEADS * DIM * DIM);
    bf16* cans  = (bf16*)carve(sizeof(bf16) * LAYERS * HEADS * DIM);
    bf16* cand  = (bf16*)carve(sizeof(bf16) * LAYERS * HEADS * DIM);
    bf16* ctw   = (bf16*)carve(sizeof(bf16) * LAYERS * DIM * HEADS * DIM);
    bf16* ctb   = (bf16*)carve(sizeof(bf16) * LAYERS * DIM);
    bf16* cp1w  = (bf16*)carve(sizeof(bf16) * LAYERS * 2 * DIM * DIM);
    bf16* cp1b  = (bf16*)carve(sizeof(bf16) * LAYERS * 2 * DIM);
    bf16* cp2w  = (bf16*)carve(sizeof(bf16) * LAYERS * 2 * DIM);
    bf16* cp2b  = (bf16*)carve(sizeof(bf16) * LAYERS);
    bf16* hbuf   = (bf16*)carve(sizeof(bf16) * N_NODES * HEADS * DIM);
    bf16* aggbuf = (bf16*)carve(sizeof(bf16) * N_NODES * HEADS * DIM);
    // h1 (gate hidden, [N, 256]) aliases hbuf: hbuf is dead between the trans
    // GEMM of layer d and the fc GEMM of layer d+1.
    bf16* h1 = hbuf;

    if (off > ws_size) {
        sentinel_kernel<<<(out_size + 255) / 256, 256, 0, stream>>>(
            (bf16*)d_out, out_size);
        return;
    }

    detect_kernel<<<1, 256, 0, stream>>>((const unsigned short*)feat_in, 65536, dflag);

    auto cvt = [&](const void* in, bf16* out, int n) {
        cvt_kernel<<<(n + 255) / 256, 256, 0, stream>>>(in, out, n, dflag);
    };
    cvt(d_in[0],  featA, N_NODES * DIM);
    cvt(d_in[4],  cfc,  LAYERS * HEADS * DIM * DIM);
    cvt(d_in[5],  cans, LAYERS * HEADS * DIM);
    cvt(d_in[6],  cand, LAYERS * HEADS * DIM);
    cvt(d_in[7],  ctw,  LAYERS * DIM * HEADS * DIM);
    cvt(d_in[8],  ctb,  LAYERS * DIM);
    cvt(d_in[9],  cp1w, LAYERS * 2 * DIM * DIM);
    cvt(d_in[10], cp1b, LAYERS * 2 * DIM);
    cvt(d_in[11], cp2w, LAYERS * 2 * DIM);
    cvt(d_in[12], cp2b, LAYERS);

    hipMemsetAsync(deg, 0, sizeof(int) * N_NODES, stream);
    hipMemsetAsync(cursor, 0, sizeof(int) * N_NODES, stream);
    hipMemsetAsync(gcnt, 0, sizeof(int) * NGRAPH, stream);
    hipMemsetAsync(out_acc, 0, sizeof(float) * NGRAPH * DIM, stream);

    count_kernel<<<(N_EDGES + 255) / 256, 256, 0, stream>>>(dst, deg, N_EDGES);
    count_kernel<<<(N_NODES + 255) / 256, 256, 0, stream>>>(gid, gcnt, N_NODES);
    scan_kernel<<<1, 256, 0, stream>>>(deg, rp, N_NODES);
    scan_kernel<<<1, 256, 0, stream>>>(gcnt, gptr, NGRAPH);
    fill_kernel<<<(N_EDGES + 255) / 256, 256, 0, stream>>>(src, dst, rp, cursor, esrc);

    bf16* fin = featA;
    bf16* fout = featB;
    for (int d = 0; d < LAYERS; ++d) {
        // h = feat @ fc_w^T : [N, 384]
        gemm_mfma<<<dim3(313, 6), 256, 0, stream>>>(
            fin, cfc + (size_t)d * HEADS * DIM * DIM, hbuf,
            N_NODES, HEADS * DIM, DIM, nullptr, nullptr, 0);
        scores_kernel<<<(N_NODES * HEADS + 3) / 4, 256, 0, stream>>>(
            hbuf, cans + (size_t)d * HEADS * DIM, cand + (size_t)d * HEADS * DIM,
            s_ns, s_nd);
        agg_kernel<<<N_NODES, 128, 0, stream>>>(hbuf, rp, esrc, s_ns, s_nd, aggbuf);
        // out = agg @ trans_w^T + b (+relu) + resid : [N, 128]
        gemm_mfma<<<dim3(313, 2), 256, 0, stream>>>(
            aggbuf, ctw + (size_t)d * DIM * HEADS * DIM, fout,
            N_NODES, DIM, HEADS * DIM, ctb + (size_t)d * DIM, fin,
            (d < LAYERS - 1) ? 1 : 0);
        // gate hidden: h1 = relu(fout @ p1w^T + p1b) : [N, 256]  (h1 aliases hbuf)
        gemm_mfma<<<dim3(313, 4), 256, 0, stream>>>(
            fout, cp1w + (size_t)d * 2 * DIM * DIM, h1,
            N_NODES, 2 * DIM, DIM, cp1b + (size_t)d * 2 * DIM, nullptr, 1);
        gate_dot<<<(N_NODES + 3) / 4, 256, 0, stream>>>(
            h1, cp2w + (size_t)d * 2 * DIM, cp2b + d, gateb);
        pool_kernel<<<NGRAPH, 128, 0, stream>>>(fout, gateb, gptr, out_acc);
        bf16* t = fin; fin = fout; fout = t;
    }
    writeout_kernel<<<(NGRAPH * DIM + 255) / 256, 256, 0, stream>>>(
        out_acc, d_out, dflag);
}

// Round 5
// 591.202 us; speedup vs baseline: 2.3444x; 1.5398x over previous
//
#include <hip/hip_runtime.h>
#include <hip/hip_bf16.h>

#define N_NODES 20000
#define N_EDGES 320000
#define DIM 128
#define HEADS 3
#define LAYERS 3
#define NGRAPH 64
#define NEG_SLOPE 0.2f

typedef const __hip_bfloat16* bfp;
typedef __hip_bfloat16 bf16;
typedef short v8s __attribute__((ext_vector_type(8)));
typedef float v4f __attribute__((ext_vector_type(4)));

__device__ __forceinline__ float b2f(unsigned short u) {
    return __uint_as_float(((unsigned)u) << 16);
}
__device__ __forceinline__ float lo2f(unsigned u) { return __uint_as_float(u << 16); }
__device__ __forceinline__ float hi2f(unsigned u) { return __uint_as_float(u & 0xffff0000u); }
__device__ __forceinline__ float leaky(float z) {
    return z >= 0.f ? z : NEG_SLOPE * z;
}
__device__ __forceinline__ unsigned packbf(float a, float b) {
    bf16 x = __float2bfloat16(a), y = __float2bfloat16(b);
    return (unsigned)*(unsigned short*)&x | ((unsigned)*(unsigned short*)&y << 16);
}

// ---------------- dtype detection (fp32 vs bf16 storage) ----------------
__global__ void detect_kernel(const unsigned short* __restrict__ probe,
                              int nshorts, int* __restrict__ flag) {
    __shared__ int cnt_s;
    if (threadIdx.x == 0) cnt_s = 0;
    __syncthreads();
    int c = 0;
    for (int i = threadIdx.x; i < nshorts; i += 256) {
        int e = (probe[i] >> 7) & 0xFF;
        if (e >= 140) ++c;
    }
    atomicAdd(&cnt_s, c);
    __syncthreads();
    if (threadIdx.x == 0) *flag = (cnt_s > 8) ? 1 : 0;
}

// fused conversion of all float inputs into bf16 ws copies
#define NCVT 10
struct CvtArgs {
    const void* src[NCVT];
    bf16* dst[NCVT];
    int n[NCVT];
};
__global__ void cvt_all_kernel(CvtArgs args, const int* __restrict__ flag) {
    int i = blockIdx.x * 256 + threadIdx.x;
    int f = *flag;
#pragma unroll
    for (int s = 0; s < NCVT; ++s) {
        int ns = args.n[s];
        if (i < ns) {
            if (f) args.dst[s][i] = __float2bfloat16(((const float*)args.src[s])[i]);
            else   args.dst[s][i] = ((const bf16*)args.src[s])[i];
            return;
        }
        i -= ns;
    }
}

// ---------------- setup kernels ----------------

__global__ void count_kernel(const int* __restrict__ idx, int* __restrict__ cnt, int n) {
    int i = blockIdx.x * 256 + threadIdx.x;
    if (i < n) atomicAdd(&cnt[idx[i]], 1);
}

__global__ void scan_kernel(const int* __restrict__ cnt, int* __restrict__ ptr, int n) {
    __shared__ int sums[256];
    int tid = threadIdx.x;
    int chunk = (n + 255) / 256;
    int b = tid * chunk;
    int e = min(b + chunk, n);
    int loc = 0;
    for (int i = b; i < e; ++i) loc += cnt[i];
    sums[tid] = loc;
    __syncthreads();
    if (tid == 0) {
        int run = 0;
        for (int j = 0; j < 256; ++j) { int t = sums[j]; sums[j] = run; run += t; }
        ptr[n] = run;
    }
    __syncthreads();
    int run = sums[tid];
    for (int i = b; i < e; ++i) { ptr[i] = run; run += cnt[i]; }
}

// node_gid is sorted: graph ranges via binary search, no atomics
__global__ void gptr_kernel(const int* __restrict__ gid, int* __restrict__ gptr) {
    int g = threadIdx.x;
    if (g > NGRAPH) return;
    int lo = 0, hi = N_NODES;
    while (lo < hi) {
        int mid = (lo + hi) >> 1;
        if (gid[mid] < g) lo = mid + 1; else hi = mid;
    }
    gptr[g] = lo;
}

__global__ void fill_kernel(const int* __restrict__ src, const int* __restrict__ dst,
                            const int* __restrict__ rp, int* __restrict__ cursor,
                            int* __restrict__ esrc) {
    int e = blockIdx.x * 256 + threadIdx.x;
    if (e < N_EDGES) {
        int d = dst[e];
        int pos = atomicAdd(&cursor[d], 1);
        esrc[rp[d] + pos] = src[e];
    }
}

__global__ void sentinel_kernel(bf16* out, int n) {
    int i = blockIdx.x * 256 + threadIdx.x;
    if (i < n) out[i] = __float2bfloat16(2.0f);
}

// ---------------- MFMA GEMM: C[M,N] = A[M,K] * B[N,K]^T (all bf16, fp32 acc) ----
__global__ __launch_bounds__(256) void gemm_mfma(
    const bf16* __restrict__ A, const bf16* __restrict__ B,
    bf16* __restrict__ C, int M, int N, int K,
    const bf16* __restrict__ bias, const bf16* __restrict__ resid,
    int do_relu)
{
    const int wave = threadIdx.x >> 6;
    const int lane = threadIdx.x & 63;
    const int quad = lane >> 4;
    const int r16  = lane & 15;
    const int m0 = blockIdx.x * 64 + wave * 16;
    const int n0 = blockIdx.y * 64;
    const int mrow = m0 + r16;
    const bool mvalid = mrow < M;
    const short* As = (const short*)A;
    const short* Bs = (const short*)B;

    v4f acc0 = {0.f, 0.f, 0.f, 0.f};
    v4f acc1 = acc0, acc2 = acc0, acc3 = acc0;

    for (int k0 = 0; k0 < K; k0 += 32) {
        v8s a = {0, 0, 0, 0, 0, 0, 0, 0};
        if (mvalid)
            a = *(const v8s*)(As + (size_t)mrow * K + k0 + quad * 8);
        const short* bp = Bs + (size_t)(n0 + r16) * K + k0 + quad * 8;
        v8s b0 = *(const v8s*)(bp);
        v8s b1 = *(const v8s*)(bp + (size_t)16 * K);
        v8s b2 = *(const v8s*)(bp + (size_t)32 * K);
        v8s b3 = *(const v8s*)(bp + (size_t)48 * K);
        acc0 = __builtin_amdgcn_mfma_f32_16x16x32_bf16(a, b0, acc0, 0, 0, 0);
        acc1 = __builtin_amdgcn_mfma_f32_16x16x32_bf16(a, b1, acc1, 0, 0, 0);
        acc2 = __builtin_amdgcn_mfma_f32_16x16x32_bf16(a, b2, acc2, 0, 0, 0);
        acc3 = __builtin_amdgcn_mfma_f32_16x16x32_bf16(a, b3, acc3, 0, 0, 0);
    }

    v4f accs[4] = {acc0, acc1, acc2, acc3};
#pragma unroll
    for (int t = 0; t < 4; ++t) {
        const int n = n0 + t * 16 + r16;
        float bb = bias ? __bfloat162float(bias[n]) : 0.f;
#pragma unroll
        for (int reg = 0; reg < 4; ++reg) {
            const int m = m0 + quad * 4 + reg;
            if (m >= M) continue;
            float v = accs[t][reg];
            if (bias) {
                v += bb;
                if (do_relu) v = fmaxf(v, 0.f);
            }
            if (resid) v += __bfloat162float(resid[(size_t)m * N + n]);
            C[(size_t)m * N + n] = __float2bfloat16(v);
        }
    }
}

// ---------------- attention scores: one wave per (node, head) ----------------
__global__ __launch_bounds__(256) void scores_kernel(
    const bf16* __restrict__ h, const bf16* __restrict__ a_ns,
    const bf16* __restrict__ a_nd,
    float* __restrict__ s_ns, float* __restrict__ s_nd)
{
    int wid = blockIdx.x * 4 + (threadIdx.x >> 6);
    if (wid >= N_NODES * HEADS) return;
    int lane = threadIdx.x & 63;
    int n = wid / HEADS, hh = wid - n * HEADS;
    const bf16* hp = h + (size_t)n * (HEADS * DIM) + hh * DIM;
    float v0 = __bfloat162float(hp[lane]);
    float v1 = __bfloat162float(hp[lane + 64]);
    float pns = v0 * __bfloat162float(a_ns[hh * DIM + lane]) +
                v1 * __bfloat162float(a_ns[hh * DIM + lane + 64]);
    float pnd = v0 * __bfloat162float(a_nd[hh * DIM + lane]) +
                v1 * __bfloat162float(a_nd[hh * DIM + lane + 64]);
    for (int o = 32; o > 0; o >>= 1) {
        pns += __shfl_down(pns, o);
        pnd += __shfl_down(pnd, o);
    }
    if (lane == 0) { s_ns[wid] = pns; s_nd[wid] = pnd; }
}

// ---------------- per-dst softmax + aggregate: one WAVE per dst node ----------
__global__ __launch_bounds__(256) void agg_kernel(
    const bf16* __restrict__ h, const int* __restrict__ rp,
    const int* __restrict__ esrc, const float* __restrict__ s_ns,
    const float* __restrict__ s_nd, bf16* __restrict__ agg)
{
    const int node = blockIdx.x * 4 + (threadIdx.x >> 6);
    if (node >= N_NODES) return;
    const int lane = threadIdx.x & 63;
    const int beg = rp[node], end = rp[node + 1];
    const int cnt = end - beg;
    unsigned* outp = (unsigned*)(agg + (size_t)node * (HEADS * DIM));
    if (cnt <= 0) {
        outp[lane] = 0u; outp[64 + lane] = 0u; outp[128 + lane] = 0u;
        return;
    }
    const float snd0 = s_nd[node * 3 + 0];
    const float snd1 = s_nd[node * 3 + 1];
    const float snd2 = s_nd[node * 3 + 2];
    // --- max per head (butterfly so all lanes hold result) ---
    float m0 = -1e30f, m1 = -1e30f, m2 = -1e30f;
    for (int i = lane; i < cnt; i += 64) {
        int s = esrc[beg + i];
        m0 = fmaxf(m0, leaky(s_ns[s * 3 + 0] + snd0));
        m1 = fmaxf(m1, leaky(s_ns[s * 3 + 1] + snd1));
        m2 = fmaxf(m2, leaky(s_ns[s * 3 + 2] + snd2));
    }
#pragma unroll
    for (int o = 32; o > 0; o >>= 1) {
        m0 = fmaxf(m0, __shfl_xor(m0, o));
        m1 = fmaxf(m1, __shfl_xor(m1, o));
        m2 = fmaxf(m2, __shfl_xor(m2, o));
    }
    // --- gather with on-the-fly p, fold sum-of-exp from the chunk lanes ---
    float ss0 = 0.f, ss1 = 0.f, ss2 = 0.f;
    float acc[6] = {0.f, 0.f, 0.f, 0.f, 0.f, 0.f};
    for (int c0 = 0; c0 < cnt; c0 += 64) {
        int ce = min(64, cnt - c0);
        int sj = 0;
        float p0 = 0.f, p1 = 0.f, p2 = 0.f;
        if (lane < ce) {
            sj = esrc[beg + c0 + lane];
            p0 = __expf(leaky(s_ns[sj * 3 + 0] + snd0) - m0);
            p1 = __expf(leaky(s_ns[sj * 3 + 1] + snd1) - m1);
            p2 = __expf(leaky(s_ns[sj * 3 + 2] + snd2) - m2);
            ss0 += p0; ss1 += p1; ss2 += p2;
        }
        for (int j = 0; j < ce; ++j) {
            int srcj = __shfl(sj, j);
            float q0 = __shfl(p0, j);
            float q1 = __shfl(p1, j);
            float q2 = __shfl(p2, j);
            const unsigned* hp = (const unsigned*)(h + (size_t)srcj * (HEADS * DIM));
            unsigned u0 = hp[lane];
            unsigned u1 = hp[64 + lane];
            unsigned u2 = hp[128 + lane];
            acc[0] += q0 * lo2f(u0); acc[1] += q0 * hi2f(u0);
            acc[2] += q1 * lo2f(u1); acc[3] += q1 * hi2f(u1);
            acc[4] += q2 * lo2f(u2); acc[5] += q2 * hi2f(u2);
        }
    }
#pragma unroll
    for (int o = 32; o > 0; o >>= 1) {
        ss0 += __shfl_xor(ss0, o);
        ss1 += __shfl_xor(ss1, o);
        ss2 += __shfl_xor(ss2, o);
    }
    float i0 = 1.f / ss0, i1 = 1.f / ss1, i2 = 1.f / ss2;
    outp[lane]       = packbf(acc[0] * i0, acc[1] * i0);
    outp[64 + lane]  = packbf(acc[2] * i1, acc[3] * i1);
    outp[128 + lane] = packbf(acc[4] * i2, acc[5] * i2);
}

// ---------------- gate second layer: one wave per node ----------------
__global__ __launch_bounds__(256) void gate_dot(
    const bf16* __restrict__ h1, const bf16* __restrict__ p2w,
    const bf16* __restrict__ p2b, float* __restrict__ gate)
{
    int node = blockIdx.x * 4 + (threadIdx.x >> 6);
    if (node >= N_NODES) return;
    int lane = threadIdx.x & 63;
    const unsigned short* hp = (const unsigned short*)(h1 + (size_t)node * 256);
    const unsigned short* wp = (const unsigned short*)p2w;
    ushort4 hv = *(const ushort4*)(hp + lane * 4);
    ushort4 wv = *(const ushort4*)(wp + lane * 4);
    float acc = b2f(hv.x) * b2f(wv.x) + b2f(hv.y) * b2f(wv.y) +
                b2f(hv.z) * b2f(wv.z) + b2f(hv.w) * b2f(wv.w);
    for (int o = 32; o > 0; o >>= 1) acc += __shfl_down(acc, o);
    if (lane == 0) gate[node] = acc + __bfloat162float(p2b[0]);
}

// ---------------- per-graph softmax stats ----------------
__global__ __launch_bounds__(128) void pool_stats(
    const float* __restrict__ gate, const int* __restrict__ gptr,
    float2* __restrict__ stats)
{
    const int g = blockIdx.x, tid = threadIdx.x;
    const int beg = gptr[g], end = gptr[g + 1];
    __shared__ float red[2];
    if (beg >= end) {
        if (tid == 0) stats[g] = make_float2(0.f, 0.f);
        return;
    }
    float m = -1e30f;
    for (int i = beg + tid; i < end; i += 128) m = fmaxf(m, gate[i]);
    for (int o = 32; o > 0; o >>= 1) m = fmaxf(m, __shfl_down(m, o));
    if ((tid & 63) == 0) red[tid >> 6] = m;
    __syncthreads();
    m = fmaxf(red[0], red[1]);
    __syncthreads();
    float s = 0.f;
    for (int i = beg + tid; i < end; i += 128) s += __expf(gate[i] - m);
    for (int o = 32; o > 0; o >>= 1) s += __shfl_down(s, o);
    if ((tid & 63) == 0) red[tid >> 6] = s;
    __syncthreads();
    if (tid == 0) stats[g] = make_float2(m, 1.f / (red[0] + red[1]));
}

// ---------------- pooled accumulation: 8 blocks x 2 node-rows per graph ------
__global__ __launch_bounds__(256) void pool_acc(
    const bf16* __restrict__ feat, const float* __restrict__ gate,
    const int* __restrict__ gptr, const float2* __restrict__ stats,
    float* __restrict__ out_acc)
{
    const int g = blockIdx.x;
    const int chunk = blockIdx.y;            // 0..7
    const int p = threadIdx.x >> 7;          // 0..1
    const int c = threadIdx.x & 127;
    const int beg = gptr[g], end = gptr[g + 1];
    const float2 st = stats[g];
    float acc = 0.f;
    for (int i = beg + chunk * 2 + p; i < end; i += 16) {
        float w = __expf(gate[i] - st.x);
        acc += w * __bfloat162float(feat[(size_t)i * DIM + c]);
    }
    acc *= st.y;
    if (acc != 0.f) atomicAdd(&out_acc[g * DIM + c], acc);
}

__global__ void writeout_kernel(const float* __restrict__ out_acc,
                                void* __restrict__ out, const int* __restrict__ flag) {
    int i = blockIdx.x * 256 + threadIdx.x;
    if (i < NGRAPH * DIM) {
        float v = out_acc[i] * (1.f / 3.f);
        if (*flag) ((float*)out)[i] = v;
        else ((bf16*)out)[i] = __float2bfloat16(v);
    }
}

// ---------------- host launcher ----------------
extern "C" void kernel_launch(void* const* d_in, const int* in_sizes, int n_in,
                              void* d_out, int out_size, void* d_ws, size_t ws_size,
                              hipStream_t stream)
{
    const void* feat_in = d_in[0];
    const int* src = (const int*)d_in[1];
    const int* dst = (const int*)d_in[2];
    const int* gid = (const int*)d_in[3];

    char* base = (char*)d_ws;
    size_t off = 0;
    auto carve = [&](size_t bytes) -> void* {
        void* p = base + off;
        off = (off + bytes + 255) & ~(size_t)255;
        return p;
    };
    int* dflag  = (int*)carve(sizeof(int));
    // deg | cursor | out_acc carved contiguously -> ONE memset
    int* deg    = (int*)carve(sizeof(int) * 2 * N_NODES + sizeof(float) * NGRAPH * DIM);
    int* cursor = deg + N_NODES;
    float* out_acc = (float*)(cursor + N_NODES);
    int* rp     = (int*)carve(sizeof(int) * (N_NODES + 1));
    int* gptr   = (int*)carve(sizeof(int) * (NGRAPH + 1));
    int* esrc   = (int*)carve(sizeof(int) * N_EDGES);
    float* s_ns = (float*)carve(sizeof(float) * N_NODES * HEADS);
    float* s_nd = (float*)carve(sizeof(float) * N_NODES * HEADS);
    float* gateb = (float*)carve(sizeof(float) * N_NODES);
    float2* pstats = (float2*)carve(sizeof(float2) * NGRAPH);
    bf16* featA = (bf16*)carve(sizeof(bf16) * N_NODES * DIM);
    bf16* featB = (bf16*)carve(sizeof(bf16) * N_NODES * DIM);
    bf16* cfc   = (bf16*)carve(sizeof(bf16) * LAYERS * HEADS * DIM * DIM);
    bf16* cans  = (bf16*)carve(sizeof(bf16) * LAYERS * HEADS * DIM);
    bf16* cand  = (bf16*)carve(sizeof(bf16) * LAYERS * HEADS * DIM);
    bf16* ctw   = (bf16*)carve(sizeof(bf16) * LAYERS * DIM * HEADS * DIM);
    bf16* ctb   = (bf16*)carve(sizeof(bf16) * LAYERS * DIM);
    bf16* cp1w  = (bf16*)carve(sizeof(bf16) * LAYERS * 2 * DIM * DIM);
    bf16* cp1b  = (bf16*)carve(sizeof(bf16) * LAYERS * 2 * DIM);
    bf16* cp2w  = (bf16*)carve(sizeof(bf16) * LAYERS * 2 * DIM);
    bf16* cp2b  = (bf16*)carve(sizeof(bf16) * LAYERS);
    bf16* hbuf   = (bf16*)carve(sizeof(bf16) * N_NODES * HEADS * DIM);
    bf16* aggbuf = (bf16*)carve(sizeof(bf16) * N_NODES * HEADS * DIM);
    bf16* h1 = hbuf;  // gate hidden aliases hbuf (dead at that point)

    if (off > ws_size) {
        sentinel_kernel<<<(out_size + 255) / 256, 256, 0, stream>>>(
            (bf16*)d_out, out_size);
        return;
    }

    detect_kernel<<<1, 256, 0, stream>>>((const unsigned short*)feat_in, 65536, dflag);

    CvtArgs ca;
    const int cvt_n[NCVT] = {
        N_NODES * DIM, LAYERS * HEADS * DIM * DIM, LAYERS * HEADS * DIM,
        LAYERS * HEADS * DIM, LAYERS * DIM * HEADS * DIM, LAYERS * DIM,
        LAYERS * 2 * DIM * DIM, LAYERS * 2 * DIM, LAYERS * 2 * DIM, LAYERS };
    bf16* cvt_dst[NCVT] = { featA, cfc, cans, cand, ctw, ctb, cp1w, cp1b, cp2w, cp2b };
    const int cvt_src_idx[NCVT] = { 0, 4, 5, 6, 7, 8, 9, 10, 11, 12 };
    int total_cvt = 0;
    for (int s = 0; s < NCVT; ++s) {
        ca.src[s] = d_in[cvt_src_idx[s]];
        ca.dst[s] = cvt_dst[s];
        ca.n[s] = cvt_n[s];
        total_cvt += cvt_n[s];
    }
    cvt_all_kernel<<<(total_cvt + 255) / 256, 256, 0, stream>>>(ca, dflag);

    hipMemsetAsync(deg, 0, sizeof(int) * 2 * N_NODES + sizeof(float) * NGRAPH * DIM,
                   stream);

    count_kernel<<<(N_EDGES + 255) / 256, 256, 0, stream>>>(dst, deg, N_EDGES);
    scan_kernel<<<1, 256, 0, stream>>>(deg, rp, N_NODES);
    gptr_kernel<<<1, 128, 0, stream>>>(gid, gptr);
    fill_kernel<<<(N_EDGES + 255) / 256, 256, 0, stream>>>(src, dst, rp, cursor, esrc);

    bf16* fin = featA;
    bf16* fout = featB;
    for (int d = 0; d < LAYERS; ++d) {
        gemm_mfma<<<dim3(313, 6), 256, 0, stream>>>(
            fin, cfc + (size_t)d * HEADS * DIM * DIM, hbuf,
            N_NODES, HEADS * DIM, DIM, nullptr, nullptr, 0);
        scores_kernel<<<(N_NODES * HEADS + 3) / 4, 256, 0, stream>>>(
            hbuf, cans + (size_t)d * HEADS * DIM, cand + (size_t)d * HEADS * DIM,
            s_ns, s_nd);
        agg_kernel<<<(N_NODES + 3) / 4, 256, 0, stream>>>(
            hbuf, rp, esrc, s_ns, s_nd, aggbuf);
        gemm_mfma<<<dim3(313, 2), 256, 0, stream>>>(
            aggbuf, ctw + (size_t)d * DIM * HEADS * DIM, fout,
            N_NODES, DIM, HEADS * DIM, ctb + (size_t)d * DIM, fin,
            (d < LAYERS - 1) ? 1 : 0);
        gemm_mfma<<<dim3(313, 4), 256, 0, stream>>>(
            fout, cp1w + (size_t)d * 2 * DIM * DIM, h1,
            N_NODES, 2 * DIM, DIM, cp1b + (size_t)d * 2 * DIM, nullptr, 1);
        gate_dot<<<(N_NODES + 3) / 4, 256, 0, stream>>>(
            h1, cp2w + (size_t)d * 2 * DIM, cp2b + d, gateb);
        pool_stats<<<NGRAPH, 128, 0, stream>>>(gateb, gptr, pstats);
        pool_acc<<<dim3(NGRAPH, 8), 256, 0, stream>>>(
            fout, gateb, gptr, pstats, out_acc);
        bf16* t = fin; fin = fout; fout = t;
    }
    writeout_kernel<<<(NGRAPH * DIM + 255) / 256, 256, 0, stream>>>(
        out_acc, d_out, dflag);
}

// Round 7
// 567.692 us; speedup vs baseline: 2.4415x; 1.0414x over previous
//
#include <hip/hip_runtime.h>
#include <hip/hip_bf16.h>

#define N_NODES 20000
#define N_EDGES 320000
#define DIM 128
#define HEADS 3
#define LAYERS 3
#define NGRAPH 64
#define NEG_SLOPE 0.2f

typedef const __hip_bfloat16* bfp;
typedef __hip_bfloat16 bf16;
typedef short v8s __attribute__((ext_vector_type(8)));
typedef float v4f __attribute__((ext_vector_type(4)));
typedef unsigned v3u __attribute__((ext_vector_type(3)));

__device__ __forceinline__ float b2f(unsigned short u) {
    return __uint_as_float(((unsigned)u) << 16);
}
__device__ __forceinline__ float lo2f(unsigned u) { return __uint_as_float(u << 16); }
__device__ __forceinline__ float hi2f(unsigned u) { return __uint_as_float(u & 0xffff0000u); }
__device__ __forceinline__ float leaky(float z) {
    return z >= 0.f ? z : NEG_SLOPE * z;
}
__device__ __forceinline__ unsigned packbf(float a, float b) {
    bf16 x = __float2bfloat16(a), y = __float2bfloat16(b);
    return (unsigned)*(unsigned short*)&x | ((unsigned)*(unsigned short*)&y << 16);
}

// ---------------- dtype detection (fp32 vs bf16 storage) ----------------
__global__ void detect_kernel(const unsigned short* __restrict__ probe,
                              int nshorts, int* __restrict__ cnt) {
    int i = blockIdx.x * 256 + threadIdx.x;
    if (i < nshorts) {
        int e = (probe[i] >> 7) & 0xFF;
        if (e >= 140) atomicAdd(cnt, 1);
    }
}

// fused conversion of all float inputs into bf16 ws copies (4 elems/thread)
#define NCVT 10
struct CvtArgs {
    const void* src[NCVT];
    bf16* dst[NCVT];
    int n4[NCVT];   // ceil(n/4)
    int n[NCVT];
};
__global__ void cvt_all_kernel(CvtArgs args, const int* __restrict__ flag) {
    int i = blockIdx.x * 256 + threadIdx.x;
    int f = (*flag) > 8;
#pragma unroll
    for (int s = 0; s < NCVT; ++s) {
        int ns4 = args.n4[s];
        if (i < ns4) {
            int ns = args.n[s];
            int base = i * 4;
            bf16* dst = args.dst[s];
            if (f) {
                const float* sp = (const float*)args.src[s];
                if (base + 3 < ns) {
                    float4 v = *(const float4*)(sp + base);
                    bf16 o0 = __float2bfloat16(v.x), o1 = __float2bfloat16(v.y);
                    bf16 o2 = __float2bfloat16(v.z), o3 = __float2bfloat16(v.w);
                    ushort4 pk = { *(unsigned short*)&o0, *(unsigned short*)&o1,
                                   *(unsigned short*)&o2, *(unsigned short*)&o3 };
                    *(ushort4*)(dst + base) = pk;
                } else {
                    for (int j = 0; j < 4 && base + j < ns; ++j)
                        dst[base + j] = __float2bfloat16(sp[base + j]);
                }
            } else {
                const bf16* sp = (const bf16*)args.src[s];
                if (base + 3 < ns) {
                    *(ushort4*)(dst + base) = *(const ushort4*)(sp + base);
                } else {
                    for (int j = 0; j < 4 && base + j < ns; ++j)
                        dst[base + j] = sp[base + j];
                }
            }
            return;
        }
        i -= ns4;
    }
}

// ---------------- setup kernels ----------------

__global__ void count_kernel(const int* __restrict__ idx, int* __restrict__ cnt, int n) {
    int i = blockIdx.x * 256 + threadIdx.x;
    if (i < n) atomicAdd(&cnt[idx[i]], 1);
}

__global__ void scan_kernel(const int* __restrict__ cnt, int* __restrict__ ptr, int n) {
    __shared__ int sums[256];
    int tid = threadIdx.x;
    int chunk = (n + 255) / 256;
    int b = tid * chunk;
    int e = min(b + chunk, n);
    int loc = 0;
    for (int i = b; i < e; ++i) loc += cnt[i];
    sums[tid] = loc;
    __syncthreads();
    if (tid == 0) {
        int run = 0;
        for (int j = 0; j < 256; ++j) { int t = sums[j]; sums[j] = run; run += t; }
        ptr[n] = run;
    }
    __syncthreads();
    int run = sums[tid];
    for (int i = b; i < e; ++i) { ptr[i] = run; run += cnt[i]; }
}

// node_gid is sorted: graph ranges via binary search, no atomics
__global__ void gptr_kernel(const int* __restrict__ gid, int* __restrict__ gptr) {
    int g = threadIdx.x;
    if (g > NGRAPH) return;
    int lo = 0, hi = N_NODES;
    while (lo < hi) {
        int mid = (lo + hi) >> 1;
        if (gid[mid] < g) lo = mid + 1; else hi = mid;
    }
    gptr[g] = lo;
}

__global__ void fill_kernel(const int* __restrict__ src, const int* __restrict__ dst,
                            const int* __restrict__ rp, int* __restrict__ cursor,
                            int* __restrict__ esrc) {
    int e = blockIdx.x * 256 + threadIdx.x;
    if (e < N_EDGES) {
        int d = dst[e];
        int pos = atomicAdd(&cursor[d], 1);
        esrc[rp[d] + pos] = src[e];
    }
}

__global__ void sentinel_kernel(bf16* out, int n) {
    int i = blockIdx.x * 256 + threadIdx.x;
    if (i < n) out[i] = __float2bfloat16(2.0f);
}

// ---------------- MFMA GEMM: C[M,N] = A[M,K] * B[N,K]^T (all bf16, fp32 acc) ----
// TB = number of 16-col tiles per wave (wave output = 16 x TB*16).
// permute_h: write C in head-interleaved layout (N must be 384).
template <int TB>
__global__ __launch_bounds__(256) void gemm_mfma(
    const bf16* __restrict__ A, const bf16* __restrict__ B,
    bf16* __restrict__ C, int M, int N, int K,
    const bf16* __restrict__ bias, const bf16* __restrict__ resid,
    int do_relu, int permute_h)
{
    const int wave = threadIdx.x >> 6;
    const int lane = threadIdx.x & 63;
    const int quad = lane >> 4;
    const int r16  = lane & 15;
    const int m0 = blockIdx.x * 64 + wave * 16;
    const int n0 = blockIdx.y * (TB * 16);
    const int mrow = m0 + r16;
    const bool mvalid = mrow < M;
    const short* As = (const short*)A;
    const short* Bs = (const short*)B;

    v4f acc[TB];
#pragma unroll
    for (int t = 0; t < TB; ++t) acc[t] = (v4f){0.f, 0.f, 0.f, 0.f};

    for (int k0 = 0; k0 < K; k0 += 32) {
        v8s a = {0, 0, 0, 0, 0, 0, 0, 0};
        if (mvalid)
            a = *(const v8s*)(As + (size_t)mrow * K + k0 + quad * 8);
        const short* bp = Bs + (size_t)(n0 + r16) * K + k0 + quad * 8;
#pragma unroll
        for (int t = 0; t < TB; ++t) {
            v8s b = *(const v8s*)(bp + (size_t)(16 * t) * K);
            acc[t] = __builtin_amdgcn_mfma_f32_16x16x32_bf16(a, b, acc[t], 0, 0, 0);
        }
    }

#pragma unroll
    for (int t = 0; t < TB; ++t) {
        const int n = n0 + t * 16 + r16;
        float bb = bias ? __bfloat162float(bias[n]) : 0.f;
#pragma unroll
        for (int reg = 0; reg < 4; ++reg) {
            const int m = m0 + quad * 4 + reg;
            if (m >= M) continue;
            float v = acc[t][reg];
            if (bias) {
                v += bb;
                if (do_relu) v = fmaxf(v, 0.f);
            }
            if (resid) v += __bfloat162float(resid[(size_t)m * N + n]);
            size_t idx;
            if (permute_h) {
                // head-interleaved: row = 64 pairs x (3 heads x 2)
                int d = n & 127, head = n >> 7;
                idx = (size_t)m * N + (size_t)((d >> 1) * 6 + head * 2 + (d & 1));
            } else {
                idx = (size_t)m * N + n;
            }
            C[idx] = __float2bfloat16(v);
        }
    }
}

// ---------------- attention scores: one wave per (node, head) ----------------
// h2 is head-interleaved: dword (pair*3 + head) = dims (2p, 2p+1) of head.
__global__ __launch_bounds__(256) void scores_kernel(
    const unsigned* __restrict__ h2, const unsigned* __restrict__ a_ns,
    const unsigned* __restrict__ a_nd,
    float* __restrict__ s_ns, float* __restrict__ s_nd)
{
    int wid = blockIdx.x * 4 + (threadIdx.x >> 6);
    if (wid >= N_NODES * HEADS) return;
    int p = threadIdx.x & 63;
    int n = wid / HEADS, hh = wid - n * HEADS;
    unsigned u = h2[(size_t)n * 192 + p * 3 + hh];
    unsigned ans = a_ns[hh * 64 + p];
    unsigned and_ = a_nd[hh * 64 + p];
    float v0 = lo2f(u), v1 = hi2f(u);
    float pns = v0 * lo2f(ans) + v1 * hi2f(ans);
    float pnd = v0 * lo2f(and_) + v1 * hi2f(and_);
    for (int o = 32; o > 0; o >>= 1) {
        pns += __shfl_down(pns, o);
        pnd += __shfl_down(pnd, o);
    }
    if (p == 0) { s_ns[wid] = pns; s_nd[wid] = pnd; }
}

// ---------------- per-dst softmax + aggregate: one WAVE per dst node ----------
// h2 head-interleaved; lane = dim-pair; per edge: one dwordx3 (12B) gather.
__global__ __launch_bounds__(256) void agg_kernel(
    const unsigned* __restrict__ h2, const int* __restrict__ rp,
    const int* __restrict__ esrc, const float* __restrict__ s_ns,
    const float* __restrict__ s_nd, bf16* __restrict__ agg)
{
    const int node = blockIdx.x * 4 + (threadIdx.x >> 6);
    if (node >= N_NODES) return;
    const int lane = threadIdx.x & 63;
    const int beg = rp[node], end = rp[node + 1];
    const int cnt = end - beg;
    unsigned* outp = (unsigned*)(agg + (size_t)node * (HEADS * DIM));
    if (cnt <= 0) {
        outp[lane] = 0u; outp[64 + lane] = 0u; outp[128 + lane] = 0u;
        return;
    }
    const float snd0 = s_nd[node * 3 + 0];
    const float snd1 = s_nd[node * 3 + 1];
    const float snd2 = s_nd[node * 3 + 2];
    float m0 = -1e30f, m1 = -1e30f, m2 = -1e30f;
    for (int i = lane; i < cnt; i += 64) {
        int s = esrc[beg + i];
        m0 = fmaxf(m0, leaky(s_ns[s * 3 + 0] + snd0));
        m1 = fmaxf(m1, leaky(s_ns[s * 3 + 1] + snd1));
        m2 = fmaxf(m2, leaky(s_ns[s * 3 + 2] + snd2));
    }
#pragma unroll
    for (int o = 32; o > 0; o >>= 1) {
        m0 = fmaxf(m0, __shfl_xor(m0, o));
        m1 = fmaxf(m1, __shfl_xor(m1, o));
        m2 = fmaxf(m2, __shfl_xor(m2, o));
    }
    float ss0 = 0.f, ss1 = 0.f, ss2 = 0.f;
    float a0 = 0.f, a1 = 0.f, a2 = 0.f, a3 = 0.f, a4 = 0.f, a5 = 0.f;
    for (int c0 = 0; c0 < cnt; c0 += 64) {
        int ce = min(64, cnt - c0);
        int sj = 0;
        float p0 = 0.f, p1 = 0.f, p2 = 0.f;
        if (lane < ce) {
            sj = esrc[beg + c0 + lane];
            p0 = __expf(leaky(s_ns[sj * 3 + 0] + snd0) - m0);
            p1 = __expf(leaky(s_ns[sj * 3 + 1] + snd1) - m1);
            p2 = __expf(leaky(s_ns[sj * 3 + 2] + snd2) - m2);
            ss0 += p0; ss1 += p1; ss2 += p2;
        }
        int j = 0;
        for (; j + 3 < ce; j += 4) {
            int s0 = __shfl(sj, j),     s1 = __shfl(sj, j + 1);
            int s2 = __shfl(sj, j + 2), s3 = __shfl(sj, j + 3);
            v3u w0 = *(const v3u*)(h2 + (size_t)s0 * 192 + lane * 3);
            v3u w1 = *(const v3u*)(h2 + (size_t)s1 * 192 + lane * 3);
            v3u w2 = *(const v3u*)(h2 + (size_t)s2 * 192 + lane * 3);
            v3u w3 = *(const v3u*)(h2 + (size_t)s3 * 192 + lane * 3);
            float q00 = __shfl(p0, j), q01 = __shfl(p1, j), q02 = __shfl(p2, j);
            float q10 = __shfl(p0, j + 1), q11 = __shfl(p1, j + 1), q12 = __shfl(p2, j + 1);
            float q20 = __shfl(p0, j + 2), q21 = __shfl(p1, j + 2), q22 = __shfl(p2, j + 2);
            float q30 = __shfl(p0, j + 3), q31 = __shfl(p1, j + 3), q32 = __shfl(p2, j + 3);
            a0 += q00 * lo2f(w0.x); a1 += q00 * hi2f(w0.x);
            a2 += q01 * lo2f(w0.y); a3 += q01 * hi2f(w0.y);
            a4 += q02 * lo2f(w0.z); a5 += q02 * hi2f(w0.z);
            a0 += q10 * lo2f(w1.x); a1 += q10 * hi2f(w1.x);
            a2 += q11 * lo2f(w1.y); a3 += q11 * hi2f(w1.y);
            a4 += q12 * lo2f(w1.z); a5 += q12 * hi2f(w1.z);
            a0 += q20 * lo2f(w2.x); a1 += q20 * hi2f(w2.x);
            a2 += q21 * lo2f(w2.y); a3 += q21 * hi2f(w2.y);
            a4 += q22 * lo2f(w2.z); a5 += q22 * hi2f(w2.z);
            a0 += q30 * lo2f(w3.x); a1 += q30 * hi2f(w3.x);
            a2 += q31 * lo2f(w3.y); a3 += q31 * hi2f(w3.y);
            a4 += q32 * lo2f(w3.z); a5 += q32 * hi2f(w3.z);
        }
        for (; j < ce; ++j) {
            int s = __shfl(sj, j);
            float q0 = __shfl(p0, j), q1 = __shfl(p1, j), q2 = __shfl(p2, j);
            v3u w = *(const v3u*)(h2 + (size_t)s * 192 + lane * 3);
            a0 += q0 * lo2f(w.x); a1 += q0 * hi2f(w.x);
            a2 += q1 * lo2f(w.y); a3 += q1 * hi2f(w.y);
            a4 += q2 * lo2f(w.z); a5 += q2 * hi2f(w.z);
        }
    }
#pragma unroll
    for (int o = 32; o > 0; o >>= 1) {
        ss0 += __shfl_xor(ss0, o);
        ss1 += __shfl_xor(ss1, o);
        ss2 += __shfl_xor(ss2, o);
    }
    float i0 = 1.f / ss0, i1 = 1.f / ss1, i2 = 1.f / ss2;
    outp[lane]       = packbf(a0 * i0, a1 * i0);
    outp[64 + lane]  = packbf(a2 * i1, a3 * i1);
    outp[128 + lane] = packbf(a4 * i2, a5 * i2);
}

// ---------------- gate second layer: one wave per node ----------------
__global__ __launch_bounds__(256) void gate_dot(
    const bf16* __restrict__ h1, const bf16* __restrict__ p2w,
    const bf16* __restrict__ p2b, float* __restrict__ gate)
{
    int node = blockIdx.x * 4 + (threadIdx.x >> 6);
    if (node >= N_NODES) return;
    int lane = threadIdx.x & 63;
    const unsigned short* hp = (const unsigned short*)(h1 + (size_t)node * 256);
    const unsigned short* wp = (const unsigned short*)p2w;
    ushort4 hv = *(const ushort4*)(hp + lane * 4);
    ushort4 wv = *(const ushort4*)(wp + lane * 4);
    float acc = b2f(hv.x) * b2f(wv.x) + b2f(hv.y) * b2f(wv.y) +
                b2f(hv.z) * b2f(wv.z) + b2f(hv.w) * b2f(wv.w);
    for (int o = 32; o > 0; o >>= 1) acc += __shfl_down(acc, o);
    if (lane == 0) gate[node] = acc + __bfloat162float(p2b[0]);
}

// ---------------- per-graph softmax stats ----------------
__global__ __launch_bounds__(128) void pool_stats(
    const float* __restrict__ gate, const int* __restrict__ gptr,
    float2* __restrict__ stats)
{
    const int g = blockIdx.x, tid = threadIdx.x;
    const int beg = gptr[g], end = gptr[g + 1];
    __shared__ float red[2];
    if (beg >= end) {
        if (tid == 0) stats[g] = make_float2(0.f, 0.f);
        return;
    }
    float m = -1e30f;
    for (int i = beg + tid; i < end; i += 128) m = fmaxf(m, gate[i]);
    for (int o = 32; o > 0; o >>= 1) m = fmaxf(m, __shfl_down(m, o));
    if ((tid & 63) == 0) red[tid >> 6] = m;
    __syncthreads();
    m = fmaxf(red[0], red[1]);
    __syncthreads();
    float s = 0.f;
    for (int i = beg + tid; i < end; i += 128) s += __expf(gate[i] - m);
    for (int o = 32; o > 0; o >>= 1) s += __shfl_down(s, o);
    if ((tid & 63) == 0) red[tid >> 6] = s;
    __syncthreads();
    if (tid == 0) stats[g] = make_float2(m, 1.f / (red[0] + red[1]));
}

// ---------------- pooled accumulation: 8 blocks x 2 node-rows per graph ------
__global__ __launch_bounds__(256) void pool_acc(
    const bf16* __restrict__ feat, const float* __restrict__ gate,
    const int* __restrict__ gptr, const float2* __restrict__ stats,
    float* __restrict__ out_acc)
{
    const int g = blockIdx.x;
    const int chunk = blockIdx.y;
    const int p = threadIdx.x >> 7;
    const int c = threadIdx.x & 127;
    const int beg = gptr[g], end = gptr[g + 1];
    const float2 st = stats[g];
    float acc = 0.f;
    for (int i = beg + chunk * 2 + p; i < end; i += 16) {
        float w = __expf(gate[i] - st.x);
        acc += w * __bfloat162float(feat[(size_t)i * DIM + c]);
    }
    acc *= st.y;
    if (acc != 0.f) atomicAdd(&out_acc[g * DIM + c], acc);
}

__global__ void writeout_kernel(const float* __restrict__ out_acc,
                                void* __restrict__ out, const int* __restrict__ flag) {
    int i = blockIdx.x * 256 + threadIdx.x;
    if (i < NGRAPH * DIM) {
        float v = out_acc[i] * (1.f / 3.f);
        if ((*flag) > 8) ((float*)out)[i] = v;
        else ((bf16*)out)[i] = __float2bfloat16(v);
    }
}

// ---------------- host launcher ----------------
extern "C" void kernel_launch(void* const* d_in, const int* in_sizes, int n_in,
                              void* d_out, int out_size, void* d_ws, size_t ws_size,
                              hipStream_t stream)
{
    const void* feat_in = d_in[0];
    const int* src = (const int*)d_in[1];
    const int* dst = (const int*)d_in[2];
    const int* gid = (const int*)d_in[3];

    char* base = (char*)d_ws;
    size_t off = 0;
    auto carve = [&](size_t bytes) -> void* {
        void* p = base + off;
        off = (off + bytes + 255) & ~(size_t)255;
        return p;
    };
    // zeroed region: dflag | deg | cursor | out_acc -> ONE memset, runs first
    size_t zbytes = 256 + sizeof(int) * 2 * N_NODES + sizeof(float) * NGRAPH * DIM;
    char* zreg  = (char*)carve(zbytes);
    int* dflag  = (int*)zreg;
    int* deg    = (int*)(zreg + 256);
    int* cursor = deg + N_NODES;
    float* out_acc = (float*)(cursor + N_NODES);
    int* rp     = (int*)carve(sizeof(int) * (N_NODES + 1));
    int* gptr   = (int*)carve(sizeof(int) * (NGRAPH + 1));
    int* esrc   = (int*)carve(sizeof(int) * N_EDGES);
    float* s_ns = (float*)carve(sizeof(float) * N_NODES * HEADS);
    float* s_nd = (float*)carve(sizeof(float) * N_NODES * HEADS);
    float* gateb = (float*)carve(sizeof(float) * N_NODES);
    float2* pstats = (float2*)carve(sizeof(float2) * NGRAPH);
    bf16* featA = (bf16*)carve(sizeof(bf16) * N_NODES * DIM);
    bf16* featB = (bf16*)carve(sizeof(bf16) * N_NODES * DIM);
    bf16* cfc   = (bf16*)carve(sizeof(bf16) * LAYERS * HEADS * DIM * DIM);
    bf16* cans  = (bf16*)carve(sizeof(bf16) * LAYERS * HEADS * DIM);
    bf16* cand  = (bf16*)carve(sizeof(bf16) * LAYERS * HEADS * DIM);
    bf16* ctw   = (bf16*)carve(sizeof(bf16) * LAYERS * DIM * HEADS * DIM);
    bf16* ctb   = (bf16*)carve(sizeof(bf16) * LAYERS * DIM);
    bf16* cp1w  = (bf16*)carve(sizeof(bf16) * LAYERS * 2 * DIM * DIM);
    bf16* cp1b  = (bf16*)carve(sizeof(bf16) * LAYERS * 2 * DIM);
    bf16* cp2w  = (bf16*)carve(sizeof(bf16) * LAYERS * 2 * DIM);
    bf16* cp2b  = (bf16*)carve(sizeof(bf16) * LAYERS);
    bf16* hbuf   = (bf16*)carve(sizeof(bf16) * N_NODES * HEADS * DIM);
    bf16* aggbuf = (bf16*)carve(sizeof(bf16) * N_NODES * HEADS * DIM);
    bf16* h1 = hbuf;  // gate hidden aliases hbuf (dead at that point)

    if (off > ws_size) {
        sentinel_kernel<<<(out_size + 255) / 256, 256, 0, stream>>>(
            (bf16*)d_out, out_size);
        return;
    }

    hipMemsetAsync(zreg, 0, zbytes, stream);
    detect_kernel<<<128, 256, 0, stream>>>(
        (const unsigned short*)feat_in, 32768, dflag);

    CvtArgs ca;
    const int cvt_n[NCVT] = {
        N_NODES * DIM, LAYERS * HEADS * DIM * DIM, LAYERS * HEADS * DIM,
        LAYERS * HEADS * DIM, LAYERS * DIM * HEADS * DIM, LAYERS * DIM,
        LAYERS * 2 * DIM * DIM, LAYERS * 2 * DIM, LAYERS * 2 * DIM, LAYERS };
    bf16* cvt_dst[NCVT] = { featA, cfc, cans, cand, ctw, ctb, cp1w, cp1b, cp2w, cp2b };
    const int cvt_src_idx[NCVT] = { 0, 4, 5, 6, 7, 8, 9, 10, 11, 12 };
    int total4 = 0;
    for (int s = 0; s < NCVT; ++s) {
        ca.src[s] = d_in[cvt_src_idx[s]];
        ca.dst[s] = cvt_dst[s];
        ca.n[s] = cvt_n[s];
        ca.n4[s] = (cvt_n[s] + 3) / 4;
        total4 += ca.n4[s];
    }
    cvt_all_kernel<<<(total4 + 255) / 256, 256, 0, stream>>>(ca, dflag);

    count_kernel<<<(N_EDGES + 255) / 256, 256, 0, stream>>>(dst, deg, N_EDGES);
    scan_kernel<<<1, 256, 0, stream>>>(deg, rp, N_NODES);
    gptr_kernel<<<1, 128, 0, stream>>>(gid, gptr);
    fill_kernel<<<(N_EDGES + 255) / 256, 256, 0, stream>>>(src, dst, rp, cursor, esrc);

    bf16* fin = featA;
    bf16* fout = featB;
    for (int d = 0; d < LAYERS; ++d) {
        // h (head-interleaved) = feat @ fc_w^T : [N, 384]
        gemm_mfma<8><<<dim3(313, 3), 256, 0, stream>>>(
            fin, cfc + (size_t)d * HEADS * DIM * DIM, hbuf,
            N_NODES, HEADS * DIM, DIM, nullptr, nullptr, 0, 1);
        scores_kernel<<<(N_NODES * HEADS + 3) / 4, 256, 0, stream>>>(
            (const unsigned*)hbuf, (const unsigned*)(cans + (size_t)d * HEADS * DIM),
            (const unsigned*)(cand + (size_t)d * HEADS * DIM), s_ns, s_nd);
        agg_kernel<<<(N_NODES + 3) / 4, 256, 0, stream>>>(
            (const unsigned*)hbuf, rp, esrc, s_ns, s_nd, aggbuf);
        gemm_mfma<4><<<dim3(313, 2), 256, 0, stream>>>(
            aggbuf, ctw + (size_t)d * DIM * HEADS * DIM, fout,
            N_NODES, DIM, HEADS * DIM, ctb + (size_t)d * DIM, fin,
            (d < LAYERS - 1) ? 1 : 0, 0);
        // gate hidden: h1 = relu(fout @ p1w^T + p1b) : [N, 256]
        // TB=8 -> 128 cols per block-y; need grid y = 2 to cover 256 cols.
        gemm_mfma<8><<<dim3(313, 2), 256, 0, stream>>>(
            fout, cp1w + (size_t)d * 2 * DIM * DIM, h1,
            N_NODES, 2 * DIM, DIM, cp1b + (size_t)d * 2 * DIM, nullptr, 1, 0);
        gate_dot<<<(N_NODES + 3) / 4, 256, 0, stream>>>(
            h1, cp2w + (size_t)d * 2 * DIM, cp2b + d, gateb);
        pool_stats<<<NGRAPH, 128, 0, stream>>>(gateb, gptr, pstats);
        pool_acc<<<dim3(NGRAPH, 8), 256, 0, stream>>>(
            fout, gateb, gptr, pstats, out_acc);
        bf16* t = fin; fin = fout; fout = t;
    }
    writeout_kernel<<<(NGRAPH * DIM + 255) / 256, 256, 0, stream>>>(
        out_acc, d_out, dflag);
}

// Round 8
// 516.288 us; speedup vs baseline: 2.6846x; 1.0996x over previous
//
#include <hip/hip_runtime.h>
#include <hip/hip_bf16.h>

#define N_NODES 20000
#define N_EDGES 320000
#define DIM 128
#define HEADS 3
#define LAYERS 3
#define NGRAPH 64
#define NEG_SLOPE 0.2f

typedef const __hip_bfloat16* bfp;
typedef __hip_bfloat16 bf16;
typedef short v8s __attribute__((ext_vector_type(8)));
typedef float v4f __attribute__((ext_vector_type(4)));
typedef unsigned v3u __attribute__((ext_vector_type(3)));

__device__ __forceinline__ float b2f(unsigned short u) {
    return __uint_as_float(((unsigned)u) << 16);
}
__device__ __forceinline__ float lo2f(unsigned u) { return __uint_as_float(u << 16); }
__device__ __forceinline__ float hi2f(unsigned u) { return __uint_as_float(u & 0xffff0000u); }
__device__ __forceinline__ float leaky(float z) {
    return z >= 0.f ? z : NEG_SLOPE * z;
}
__device__ __forceinline__ unsigned packbf(float a, float b) {
    bf16 x = __float2bfloat16(a), y = __float2bfloat16(b);
    return (unsigned)*(unsigned short*)&x | ((unsigned)*(unsigned short*)&y << 16);
}

// ---------------- dtype detection (fp32 vs bf16 storage) ----------------
__global__ void detect_kernel(const unsigned short* __restrict__ probe,
                              int nshorts, int* __restrict__ cnt) {
    int i = blockIdx.x * 256 + threadIdx.x;
    if (i < nshorts) {
        int e = (probe[i] >> 7) & 0xFF;
        if (e >= 140) atomicAdd(cnt, 1);
    }
}

// fused conversion of all float inputs into bf16 ws copies (4 elems/thread)
#define NCVT 9
struct CvtArgs {
    const void* src[NCVT];
    bf16* dst[NCVT];
    int n4[NCVT];   // ceil(n/4)
    int n[NCVT];
};
__global__ void cvt_all_kernel(CvtArgs args, const int* __restrict__ flag) {
    int i = blockIdx.x * 256 + threadIdx.x;
    int f = (*flag) > 8;
#pragma unroll
    for (int s = 0; s < NCVT; ++s) {
        int ns4 = args.n4[s];
        if (i < ns4) {
            int ns = args.n[s];
            int base = i * 4;
            bf16* dst = args.dst[s];
            if (f) {
                const float* sp = (const float*)args.src[s];
                if (base + 3 < ns) {
                    float4 v = *(const float4*)(sp + base);
                    bf16 o0 = __float2bfloat16(v.x), o1 = __float2bfloat16(v.y);
                    bf16 o2 = __float2bfloat16(v.z), o3 = __float2bfloat16(v.w);
                    ushort4 pk = { *(unsigned short*)&o0, *(unsigned short*)&o1,
                                   *(unsigned short*)&o2, *(unsigned short*)&o3 };
                    *(ushort4*)(dst + base) = pk;
                } else {
                    for (int j = 0; j < 4 && base + j < ns; ++j)
                        dst[base + j] = __float2bfloat16(sp[base + j]);
                }
            } else {
                const bf16* sp = (const bf16*)args.src[s];
                if (base + 3 < ns) {
                    *(ushort4*)(dst + base) = *(const ushort4*)(sp + base);
                } else {
                    for (int j = 0; j < 4 && base + j < ns; ++j)
                        dst[base + j] = sp[base + j];
                }
            }
            return;
        }
        i -= ns4;
    }
}

// ---------------- setup kernels ----------------

__global__ void count_kernel(const int* __restrict__ idx, int* __restrict__ cnt, int n) {
    int i = blockIdx.x * 256 + threadIdx.x;
    if (i < n) atomicAdd(&cnt[idx[i]], 1);
}

__global__ void scan_kernel(const int* __restrict__ cnt, int* __restrict__ ptr, int n) {
    __shared__ int sums[256];
    int tid = threadIdx.x;
    int chunk = (n + 255) / 256;
    int b = tid * chunk;
    int e = min(b + chunk, n);
    int loc = 0;
    for (int i = b; i < e; ++i) loc += cnt[i];
    sums[tid] = loc;
    __syncthreads();
    if (tid == 0) {
        int run = 0;
        for (int j = 0; j < 256; ++j) { int t = sums[j]; sums[j] = run; run += t; }
        ptr[n] = run;
    }
    __syncthreads();
    int run = sums[tid];
    for (int i = b; i < e; ++i) { ptr[i] = run; run += cnt[i]; }
}

// node_gid is sorted: graph ranges via binary search, no atomics
__global__ void gptr_kernel(const int* __restrict__ gid, int* __restrict__ gptr) {
    int g = threadIdx.x;
    if (g > NGRAPH) return;
    int lo = 0, hi = N_NODES;
    while (lo < hi) {
        int mid = (lo + hi) >> 1;
        if (gid[mid] < g) lo = mid + 1; else hi = mid;
    }
    gptr[g] = lo;
}

__global__ void fill_kernel(const int* __restrict__ src, const int* __restrict__ dst,
                            const int* __restrict__ rp, int* __restrict__ cursor,
                            int* __restrict__ esrc) {
    int e = blockIdx.x * 256 + threadIdx.x;
    if (e < N_EDGES) {
        int d = dst[e];
        int pos = atomicAdd(&cursor[d], 1);
        esrc[rp[d] + pos] = src[e];
    }
}

__global__ void sentinel_kernel(bf16* out, int n) {
    int i = blockIdx.x * 256 + threadIdx.x;
    if (i < n) out[i] = __float2bfloat16(2.0f);
}

// ---------------- MFMA GEMM: C[M,N] = A[M,K] * B[N,K]^T (all bf16, fp32 acc) ----
// MODE 0: plain C write (+bias/relu/resid)
// MODE 1: head-interleaved C write + fused attention scores (N=384, TB=8,
//         blockIdx.y == head; ans/and per-head vectors; s_ns/s_nd out).
// MODE 2: NO C write; fused gate layer-2: relu(acc+bias) . p2w -> atomic gateb.
template <int TB, int MODE>
__global__ __launch_bounds__(256) void gemm_mfma(
    const bf16* __restrict__ A, const bf16* __restrict__ B,
    bf16* __restrict__ C, int M, int N, int K,
    const bf16* __restrict__ bias, const bf16* __restrict__ resid,
    int do_relu,
    const bf16* __restrict__ ans, const bf16* __restrict__ and_,
    float* __restrict__ s_ns, float* __restrict__ s_nd,
    const bf16* __restrict__ p2w, float* __restrict__ gateb)
{
    const int wave = threadIdx.x >> 6;
    const int lane = threadIdx.x & 63;
    const int quad = lane >> 4;
    const int r16  = lane & 15;
    const int m0 = blockIdx.x * 64 + wave * 16;
    const int n0 = blockIdx.y * (TB * 16);
    const int mrow = m0 + r16;
    const bool mvalid = mrow < M;
    const short* As = (const short*)A;
    const short* Bs = (const short*)B;

    v4f acc[TB];
#pragma unroll
    for (int t = 0; t < TB; ++t) acc[t] = (v4f){0.f, 0.f, 0.f, 0.f};

    for (int k0 = 0; k0 < K; k0 += 32) {
        v8s a = {0, 0, 0, 0, 0, 0, 0, 0};
        if (mvalid)
            a = *(const v8s*)(As + (size_t)mrow * K + k0 + quad * 8);
        const short* bp = Bs + (size_t)(n0 + r16) * K + k0 + quad * 8;
#pragma unroll
        for (int t = 0; t < TB; ++t) {
            v8s b = *(const v8s*)(bp + (size_t)(16 * t) * K);
            acc[t] = __builtin_amdgcn_mfma_f32_16x16x32_bf16(a, b, acc[t], 0, 0, 0);
        }
    }

    if (MODE == 2) {
        // fused gate: g[m] += sum_n relu(acc[m,n]+bias[n]) * p2w[n]
        float pwv[TB], bbv[TB];
#pragma unroll
        for (int t = 0; t < TB; ++t) {
            int n = n0 + t * 16 + r16;
            pwv[t] = __bfloat162float(p2w[n]);
            bbv[t] = __bfloat162float(bias[n]);
        }
#pragma unroll
        for (int reg = 0; reg < 4; ++reg) {
            float g = 0.f;
#pragma unroll
            for (int t = 0; t < TB; ++t)
                g += fmaxf(acc[t][reg] + bbv[t], 0.f) * pwv[t];
#pragma unroll
            for (int o = 1; o < 16; o <<= 1) g += __shfl_xor(g, o);
            int m = m0 + quad * 4 + reg;
            if (r16 == 0 && m < M) atomicAdd(&gateb[m], g);
        }
        return;
    }

    // C write (MODE 0 / 1)
#pragma unroll
    for (int t = 0; t < TB; ++t) {
        const int n = n0 + t * 16 + r16;
        float bb = bias ? __bfloat162float(bias[n]) : 0.f;
#pragma unroll
        for (int reg = 0; reg < 4; ++reg) {
            const int m = m0 + quad * 4 + reg;
            if (m >= M) continue;
            float v = acc[t][reg];
            if (bias) {
                v += bb;
                if (do_relu) v = fmaxf(v, 0.f);
            }
            if (resid) v += __bfloat162float(resid[(size_t)m * N + n]);
            size_t idx;
            if (MODE == 1) {
                // head-interleaved: dword (pair*3+head) holds dims (2p,2p+1)
                int d = n & 127, head = n >> 7;
                idx = (size_t)m * N + (size_t)((d >> 1) * 6 + head * 2 + (d & 1));
            } else {
                idx = (size_t)m * N + n;
            }
            C[idx] = __float2bfloat16(v);
        }
    }

    if (MODE == 1) {
        // fused scores: this block's 128 cols == one full head (blockIdx.y)
        const int head = blockIdx.y;
        float ansv[TB], andv[TB];
#pragma unroll
        for (int t = 0; t < TB; ++t) {
            int dcol = t * 16 + r16;
            ansv[t] = __bfloat162float(ans[head * 128 + dcol]);
            andv[t] = __bfloat162float(and_[head * 128 + dcol]);
        }
#pragma unroll
        for (int reg = 0; reg < 4; ++reg) {
            float pns = 0.f, pnd = 0.f;
#pragma unroll
            for (int t = 0; t < TB; ++t) {
                pns += acc[t][reg] * ansv[t];
                pnd += acc[t][reg] * andv[t];
            }
#pragma unroll
            for (int o = 1; o < 16; o <<= 1) {
                pns += __shfl_xor(pns, o);
                pnd += __shfl_xor(pnd, o);
            }
            int m = m0 + quad * 4 + reg;
            if (r16 == 0 && m < M) {
                s_ns[m * 3 + head] = pns;
                s_nd[m * 3 + head] = pnd;
            }
        }
    }
}

// ---------------- per-dst softmax + aggregate: one WAVE per dst node ----------
// Shuffle-free: every lane loads the same esrc/s_ns addresses (HW broadcast)
// and computes identical p values; gathers stay the only scattered traffic.
__global__ __launch_bounds__(256) void agg_kernel(
    const unsigned* __restrict__ h2, const int* __restrict__ rp,
    const int* __restrict__ esrc, const float* __restrict__ s_ns,
    const float* __restrict__ s_nd, bf16* __restrict__ agg)
{
    const int node = blockIdx.x * 4 + (threadIdx.x >> 6);
    if (node >= N_NODES) return;
    const int lane = threadIdx.x & 63;
    const int beg = rp[node], end = rp[node + 1];
    const int cnt = end - beg;
    unsigned* outp = (unsigned*)(agg + (size_t)node * (HEADS * DIM));
    if (cnt <= 0) {
        outp[lane] = 0u; outp[64 + lane] = 0u; outp[128 + lane] = 0u;
        return;
    }
    const float snd0 = s_nd[node * 3 + 0];
    const float snd1 = s_nd[node * 3 + 1];
    const float snd2 = s_nd[node * 3 + 2];
    // pass 1: max per head (lane-strided + butterfly)
    float m0 = -1e30f, m1 = -1e30f, m2 = -1e30f;
    for (int i = lane; i < cnt; i += 64) {
        int s = esrc[beg + i];
        m0 = fmaxf(m0, leaky(s_ns[s * 3 + 0] + snd0));
        m1 = fmaxf(m1, leaky(s_ns[s * 3 + 1] + snd1));
        m2 = fmaxf(m2, leaky(s_ns[s * 3 + 2] + snd2));
    }
#pragma unroll
    for (int o = 32; o > 0; o >>= 1) {
        m0 = fmaxf(m0, __shfl_xor(m0, o));
        m1 = fmaxf(m1, __shfl_xor(m1, o));
        m2 = fmaxf(m2, __shfl_xor(m2, o));
    }
    // pass 2: wave-uniform edge loop; no cross-lane ops in the chain
    float ss0 = 0.f, ss1 = 0.f, ss2 = 0.f;
    float a0 = 0.f, a1 = 0.f, a2 = 0.f, a3 = 0.f, a4 = 0.f, a5 = 0.f;
#pragma unroll 4
    for (int j = 0; j < cnt; ++j) {
        int s = esrc[beg + j];                       // same addr all lanes
        float p0 = __expf(leaky(s_ns[s * 3 + 0] + snd0) - m0);
        float p1 = __expf(leaky(s_ns[s * 3 + 1] + snd1) - m1);
        float p2 = __expf(leaky(s_ns[s * 3 + 2] + snd2) - m2);
        ss0 += p0; ss1 += p1; ss2 += p2;             // identical in all lanes
        v3u w = *(const v3u*)(h2 + (size_t)s * 192 + lane * 3);
        a0 += p0 * lo2f(w.x); a1 += p0 * hi2f(w.x);
        a2 += p1 * lo2f(w.y); a3 += p1 * hi2f(w.y);
        a4 += p2 * lo2f(w.z); a5 += p2 * hi2f(w.z);
    }
    float i0 = 1.f / ss0, i1 = 1.f / ss1, i2 = 1.f / ss2;
    outp[lane]       = packbf(a0 * i0, a1 * i0);
    outp[64 + lane]  = packbf(a2 * i1, a3 * i1);
    outp[128 + lane] = packbf(a4 * i2, a5 * i2);
}

// ---------------- per-graph softmax stats ----------------
__global__ __launch_bounds__(128) void pool_stats(
    const float* __restrict__ gate, const int* __restrict__ gptr,
    float2* __restrict__ stats)
{
    const int g = blockIdx.x, tid = threadIdx.x;
    const int beg = gptr[g], end = gptr[g + 1];
    __shared__ float red[2];
    if (beg >= end) {
        if (tid == 0) stats[g] = make_float2(0.f, 0.f);
        return;
    }
    float m = -1e30f;
    for (int i = beg + tid; i < end; i += 128) m = fmaxf(m, gate[i]);
    for (int o = 32; o > 0; o >>= 1) m = fmaxf(m, __shfl_down(m, o));
    if ((tid & 63) == 0) red[tid >> 6] = m;
    __syncthreads();
    m = fmaxf(red[0], red[1]);
    __syncthreads();
    float s = 0.f;
    for (int i = beg + tid; i < end; i += 128) s += __expf(gate[i] - m);
    for (int o = 32; o > 0; o >>= 1) s += __shfl_down(s, o);
    if ((tid & 63) == 0) red[tid >> 6] = s;
    __syncthreads();
    if (tid == 0) stats[g] = make_float2(m, 1.f / (red[0] + red[1]));
}

// ---------------- pooled accumulation: 8 blocks x 2 node-rows per graph ------
__global__ __launch_bounds__(256) void pool_acc(
    const bf16* __restrict__ feat, const float* __restrict__ gate,
    const int* __restrict__ gptr, const float2* __restrict__ stats,
    float* __restrict__ out_acc)
{
    const int g = blockIdx.x;
    const int chunk = blockIdx.y;
    const int p = threadIdx.x >> 7;
    const int c = threadIdx.x & 127;
    const int beg = gptr[g], end = gptr[g + 1];
    const float2 st = stats[g];
    float acc = 0.f;
    for (int i = beg + chunk * 2 + p; i < end; i += 16) {
        float w = __expf(gate[i] - st.x);
        acc += w * __bfloat162float(feat[(size_t)i * DIM + c]);
    }
    acc *= st.y;
    if (acc != 0.f) atomicAdd(&out_acc[g * DIM + c], acc);
}

__global__ void writeout_kernel(const float* __restrict__ out_acc,
                                void* __restrict__ out, const int* __restrict__ flag) {
    int i = blockIdx.x * 256 + threadIdx.x;
    if (i < NGRAPH * DIM) {
        float v = out_acc[i] * (1.f / 3.f);
        if ((*flag) > 8) ((float*)out)[i] = v;
        else ((bf16*)out)[i] = __float2bfloat16(v);
    }
}

// ---------------- host launcher ----------------
extern "C" void kernel_launch(void* const* d_in, const int* in_sizes, int n_in,
                              void* d_out, int out_size, void* d_ws, size_t ws_size,
                              hipStream_t stream)
{
    const void* feat_in = d_in[0];
    const int* src = (const int*)d_in[1];
    const int* dst = (const int*)d_in[2];
    const int* gid = (const int*)d_in[3];

    char* base = (char*)d_ws;
    size_t off = 0;
    auto carve = [&](size_t bytes) -> void* {
        void* p = base + off;
        off = (off + bytes + 255) & ~(size_t)255;
        return p;
    };
    // zeroed region: dflag | deg | cursor | out_acc | gateb[3] -> ONE memset
    size_t zbytes = 256 + sizeof(int) * 2 * N_NODES + sizeof(float) * NGRAPH * DIM
                  + sizeof(float) * LAYERS * N_NODES;
    char* zreg  = (char*)carve(zbytes);
    int* dflag  = (int*)zreg;
    int* deg    = (int*)(zreg + 256);
    int* cursor = deg + N_NODES;
    float* out_acc = (float*)(cursor + N_NODES);
    float* gateb3  = out_acc + NGRAPH * DIM;   // 3 per-layer gate buffers
    int* rp     = (int*)carve(sizeof(int) * (N_NODES + 1));
    int* gptr   = (int*)carve(sizeof(int) * (NGRAPH + 1));
    int* esrc   = (int*)carve(sizeof(int) * N_EDGES);
    float* s_ns = (float*)carve(sizeof(float) * N_NODES * HEADS);
    float* s_nd = (float*)carve(sizeof(float) * N_NODES * HEADS);
    float2* pstats = (float2*)carve(sizeof(float2) * NGRAPH);
    bf16* featA = (bf16*)carve(sizeof(bf16) * N_NODES * DIM);
    bf16* featB = (bf16*)carve(sizeof(bf16) * N_NODES * DIM);
    bf16* cfc   = (bf16*)carve(sizeof(bf16) * LAYERS * HEADS * DIM * DIM);
    bf16* cans  = (bf16*)carve(sizeof(bf16) * LAYERS * HEADS * DIM);
    bf16* cand  = (bf16*)carve(sizeof(bf16) * LAYERS * HEADS * DIM);
    bf16* ctw   = (bf16*)carve(sizeof(bf16) * LAYERS * DIM * HEADS * DIM);
    bf16* ctb   = (bf16*)carve(sizeof(bf16) * LAYERS * DIM);
    bf16* cp1w  = (bf16*)carve(sizeof(bf16) * LAYERS * 2 * DIM * DIM);
    bf16* cp1b  = (bf16*)carve(sizeof(bf16) * LAYERS * 2 * DIM);
    bf16* cp2w  = (bf16*)carve(sizeof(bf16) * LAYERS * 2 * DIM);
    bf16* hbuf   = (bf16*)carve(sizeof(bf16) * N_NODES * HEADS * DIM);
    bf16* aggbuf = (bf16*)carve(sizeof(bf16) * N_NODES * HEADS * DIM);

    if (off > ws_size) {
        sentinel_kernel<<<(out_size + 255) / 256, 256, 0, stream>>>(
            (bf16*)d_out, out_size);
        return;
    }

    hipMemsetAsync(zreg, 0, zbytes, stream);
    detect_kernel<<<128, 256, 0, stream>>>(
        (const unsigned short*)feat_in, 32768, dflag);

    CvtArgs ca;
    const int cvt_n[NCVT] = {
        N_NODES * DIM, LAYERS * HEADS * DIM * DIM, LAYERS * HEADS * DIM,
        LAYERS * HEADS * DIM, LAYERS * DIM * HEADS * DIM, LAYERS * DIM,
        LAYERS * 2 * DIM * DIM, LAYERS * 2 * DIM, LAYERS * 2 * DIM };
    bf16* cvt_dst[NCVT] = { featA, cfc, cans, cand, ctw, ctb, cp1w, cp1b, cp2w };
    const int cvt_src_idx[NCVT] = { 0, 4, 5, 6, 7, 8, 9, 10, 11 };
    int total4 = 0;
    for (int s = 0; s < NCVT; ++s) {
        ca.src[s] = d_in[cvt_src_idx[s]];
        ca.dst[s] = cvt_dst[s];
        ca.n[s] = cvt_n[s];
        ca.n4[s] = (cvt_n[s] + 3) / 4;
        total4 += ca.n4[s];
    }
    cvt_all_kernel<<<(total4 + 255) / 256, 256, 0, stream>>>(ca, dflag);

    count_kernel<<<(N_EDGES + 255) / 256, 256, 0, stream>>>(dst, deg, N_EDGES);
    scan_kernel<<<1, 256, 0, stream>>>(deg, rp, N_NODES);
    gptr_kernel<<<1, 128, 0, stream>>>(gid, gptr);
    fill_kernel<<<(N_EDGES + 255) / 256, 256, 0, stream>>>(src, dst, rp, cursor, esrc);

    bf16* fin = featA;
    bf16* fout = featB;
    for (int d = 0; d < LAYERS; ++d) {
        float* gateb = gateb3 + (size_t)d * N_NODES;
        // h (head-interleaved) = feat @ fc_w^T + fused scores : [N, 384]
        gemm_mfma<8, 1><<<dim3(313, 3), 256, 0, stream>>>(
            fin, cfc + (size_t)d * HEADS * DIM * DIM, hbuf,
            N_NODES, HEADS * DIM, DIM, nullptr, nullptr, 0,
            cans + (size_t)d * HEADS * DIM, cand + (size_t)d * HEADS * DIM,
            s_ns, s_nd, nullptr, nullptr);
        agg_kernel<<<(N_NODES + 3) / 4, 256, 0, stream>>>(
            (const unsigned*)hbuf, rp, esrc, s_ns, s_nd, aggbuf);
        gemm_mfma<4, 0><<<dim3(313, 2), 256, 0, stream>>>(
            aggbuf, ctw + (size_t)d * DIM * HEADS * DIM, fout,
            N_NODES, DIM, HEADS * DIM, ctb + (size_t)d * DIM, fin,
            (d < LAYERS - 1) ? 1 : 0, nullptr, nullptr, nullptr, nullptr,
            nullptr, nullptr);
        // gate: fused layer1+layer2, no h1 materialization (p2b dropped:
        // softmax is shift-invariant)
        gemm_mfma<8, 2><<<dim3(313, 2), 256, 0, stream>>>(
            fout, cp1w + (size_t)d * 2 * DIM * DIM, nullptr,
            N_NODES, 2 * DIM, DIM, cp1b + (size_t)d * 2 * DIM, nullptr, 1,
            nullptr, nullptr, nullptr, nullptr,
            cp2w + (size_t)d * 2 * DIM, gateb);
        pool_stats<<<NGRAPH, 128, 0, stream>>>(gateb, gptr, pstats);
        pool_acc<<<dim3(NGRAPH, 8), 256, 0, stream>>>(
            fout, gateb, gptr, pstats, out_acc);
        bf16* t = fin; fin = fout; fout = t;
    }
    writeout_kernel<<<(NGRAPH * DIM + 255) / 256, 256, 0, stream>>>(
        out_acc, d_out, dflag);
}

// Round 9
// 509.473 us; speedup vs baseline: 2.7205x; 1.0134x over previous
//
#include <hip/hip_runtime.h>
#include <hip/hip_bf16.h>

#define N_NODES 20000
#define N_EDGES 320000
#define DIM 128
#define HEADS 3
#define LAYERS 3
#define NGRAPH 64
#define NEG_SLOPE 0.2f

typedef const __hip_bfloat16* bfp;
typedef __hip_bfloat16 bf16;
typedef short v8s __attribute__((ext_vector_type(8)));
typedef float v4f __attribute__((ext_vector_type(4)));
typedef unsigned v3u __attribute__((ext_vector_type(3)));

__device__ __forceinline__ float b2f(unsigned short u) {
    return __uint_as_float(((unsigned)u) << 16);
}
__device__ __forceinline__ float lo2f(unsigned u) { return __uint_as_float(u << 16); }
__device__ __forceinline__ float hi2f(unsigned u) { return __uint_as_float(u & 0xffff0000u); }
__device__ __forceinline__ float leaky(float z) {
    return z >= 0.f ? z : NEG_SLOPE * z;
}
__device__ __forceinline__ unsigned packbf(float a, float b) {
    bf16 x = __float2bfloat16(a), y = __float2bfloat16(b);
    return (unsigned)*(unsigned short*)&x | ((unsigned)*(unsigned short*)&y << 16);
}

// ---------------- dtype detection (fp32 vs bf16 storage) ----------------
__global__ void detect_kernel(const unsigned short* __restrict__ probe,
                              int nshorts, int* __restrict__ cnt) {
    int i = blockIdx.x * 256 + threadIdx.x;
    if (i < nshorts) {
        int e = (probe[i] >> 7) & 0xFF;
        if (e >= 140) atomicAdd(cnt, 1);
    }
}

// fused conversion of all float inputs into bf16 ws copies (4 elems/thread)
#define NCVT 9
struct CvtArgs {
    const void* src[NCVT];
    bf16* dst[NCVT];
    int n4[NCVT];   // ceil(n/4)
    int n[NCVT];
};
__global__ void cvt_all_kernel(CvtArgs args, const int* __restrict__ flag) {
    int i = blockIdx.x * 256 + threadIdx.x;
    int f = (*flag) > 8;
#pragma unroll
    for (int s = 0; s < NCVT; ++s) {
        int ns4 = args.n4[s];
        if (i < ns4) {
            int ns = args.n[s];
            int base = i * 4;
            bf16* dst = args.dst[s];
            if (f) {
                const float* sp = (const float*)args.src[s];
                if (base + 3 < ns) {
                    float4 v = *(const float4*)(sp + base);
                    bf16 o0 = __float2bfloat16(v.x), o1 = __float2bfloat16(v.y);
                    bf16 o2 = __float2bfloat16(v.z), o3 = __float2bfloat16(v.w);
                    ushort4 pk = { *(unsigned short*)&o0, *(unsigned short*)&o1,
                                   *(unsigned short*)&o2, *(unsigned short*)&o3 };
                    *(ushort4*)(dst + base) = pk;
                } else {
                    for (int j = 0; j < 4 && base + j < ns; ++j)
                        dst[base + j] = __float2bfloat16(sp[base + j]);
                }
            } else {
                const bf16* sp = (const bf16*)args.src[s];
                if (base + 3 < ns) {
                    *(ushort4*)(dst + base) = *(const ushort4*)(sp + base);
                } else {
                    for (int j = 0; j < 4 && base + j < ns; ++j)
                        dst[base + j] = sp[base + j];
                }
            }
            return;
        }
        i -= ns4;
    }
}

// ---------------- setup kernels ----------------

__global__ void count_kernel(const int* __restrict__ idx, int* __restrict__ cnt, int n) {
    int i = blockIdx.x * 256 + threadIdx.x;
    if (i < n) atomicAdd(&cnt[idx[i]], 1);
}

__global__ void scan_kernel(const int* __restrict__ cnt, int* __restrict__ ptr, int n) {
    __shared__ int sums[256];
    int tid = threadIdx.x;
    int chunk = (n + 255) / 256;
    int b = tid * chunk;
    int e = min(b + chunk, n);
    int loc = 0;
    for (int i = b; i < e; ++i) loc += cnt[i];
    sums[tid] = loc;
    __syncthreads();
    if (tid == 0) {
        int run = 0;
        for (int j = 0; j < 256; ++j) { int t = sums[j]; sums[j] = run; run += t; }
        ptr[n] = run;
    }
    __syncthreads();
    int run = sums[tid];
    for (int i = b; i < e; ++i) { ptr[i] = run; run += cnt[i]; }
}

// node_gid is sorted: graph ranges via binary search, no atomics
__global__ void gptr_kernel(const int* __restrict__ gid, int* __restrict__ gptr) {
    int g = threadIdx.x;
    if (g > NGRAPH) return;
    int lo = 0, hi = N_NODES;
    while (lo < hi) {
        int mid = (lo + hi) >> 1;
        if (gid[mid] < g) lo = mid + 1; else hi = mid;
    }
    gptr[g] = lo;
}

// build CSR: store src AND dst per CSR slot (dst needed by pedge_kernel)
__global__ void fill_kernel(const int* __restrict__ src, const int* __restrict__ dst,
                            const int* __restrict__ rp, int* __restrict__ cursor,
                            int* __restrict__ esrc, int* __restrict__ edst) {
    int e = blockIdx.x * 256 + threadIdx.x;
    if (e < N_EDGES) {
        int d = dst[e];
        int pos = rp[d] + atomicAdd(&cursor[d], 1);
        esrc[pos] = src[e];
        edst[pos] = d;
    }
}

__global__ void sentinel_kernel(bf16* out, int n) {
    int i = blockIdx.x * 256 + threadIdx.x;
    if (i < n) out[i] = __float2bfloat16(2.0f);
}

// ---------------- MFMA GEMM: C[M,N] = A[M,K] * B[N,K]^T (all bf16, fp32 acc) ----
// MODE 0: plain C write (+bias/relu/resid)
// MODE 1: head-interleaved C write + fused attention scores (N=384, TB=8,
//         blockIdx.y == head; ans/and per-head vectors; s_ns/s_nd out).
// MODE 2: NO C write; fused gate layer-2: relu(acc+bias) . p2w -> atomic gateb.
template <int TB, int MODE>
__global__ __launch_bounds__(256) void gemm_mfma(
    const bf16* __restrict__ A, const bf16* __restrict__ B,
    bf16* __restrict__ C, int M, int N, int K,
    const bf16* __restrict__ bias, const bf16* __restrict__ resid,
    int do_relu,
    const bf16* __restrict__ ans, const bf16* __restrict__ and_,
    float* __restrict__ s_ns, float* __restrict__ s_nd,
    const bf16* __restrict__ p2w, float* __restrict__ gateb)
{
    const int wave = threadIdx.x >> 6;
    const int lane = threadIdx.x & 63;
    const int quad = lane >> 4;
    const int r16  = lane & 15;
    const int m0 = blockIdx.x * 64 + wave * 16;
    const int n0 = blockIdx.y * (TB * 16);
    const int mrow = m0 + r16;
    const bool mvalid = mrow < M;
    const short* As = (const short*)A;
    const short* Bs = (const short*)B;

    v4f acc[TB];
#pragma unroll
    for (int t = 0; t < TB; ++t) acc[t] = (v4f){0.f, 0.f, 0.f, 0.f};

    for (int k0 = 0; k0 < K; k0 += 32) {
        v8s a = {0, 0, 0, 0, 0, 0, 0, 0};
        if (mvalid)
            a = *(const v8s*)(As + (size_t)mrow * K + k0 + quad * 8);
        const short* bp = Bs + (size_t)(n0 + r16) * K + k0 + quad * 8;
#pragma unroll
        for (int t = 0; t < TB; ++t) {
            v8s b = *(const v8s*)(bp + (size_t)(16 * t) * K);
            acc[t] = __builtin_amdgcn_mfma_f32_16x16x32_bf16(a, b, acc[t], 0, 0, 0);
        }
    }

    if (MODE == 2) {
        float pwv[TB], bbv[TB];
#pragma unroll
        for (int t = 0; t < TB; ++t) {
            int n = n0 + t * 16 + r16;
            pwv[t] = __bfloat162float(p2w[n]);
            bbv[t] = __bfloat162float(bias[n]);
        }
#pragma unroll
        for (int reg = 0; reg < 4; ++reg) {
            float g = 0.f;
#pragma unroll
            for (int t = 0; t < TB; ++t)
                g += fmaxf(acc[t][reg] + bbv[t], 0.f) * pwv[t];
#pragma unroll
            for (int o = 1; o < 16; o <<= 1) g += __shfl_xor(g, o);
            int m = m0 + quad * 4 + reg;
            if (r16 == 0 && m < M) atomicAdd(&gateb[m], g);
        }
        return;
    }

#pragma unroll
    for (int t = 0; t < TB; ++t) {
        const int n = n0 + t * 16 + r16;
        float bb = bias ? __bfloat162float(bias[n]) : 0.f;
#pragma unroll
        for (int reg = 0; reg < 4; ++reg) {
            const int m = m0 + quad * 4 + reg;
            if (m >= M) continue;
            float v = acc[t][reg];
            if (bias) {
                v += bb;
                if (do_relu) v = fmaxf(v, 0.f);
            }
            if (resid) v += __bfloat162float(resid[(size_t)m * N + n]);
            size_t idx;
            if (MODE == 1) {
                int d = n & 127, head = n >> 7;
                idx = (size_t)m * N + (size_t)((d >> 1) * 6 + head * 2 + (d & 1));
            } else {
                idx = (size_t)m * N + n;
            }
            C[idx] = __float2bfloat16(v);
        }
    }

    if (MODE == 1) {
        const int head = blockIdx.y;
        float ansv[TB], andv[TB];
#pragma unroll
        for (int t = 0; t < TB; ++t) {
            int dcol = t * 16 + r16;
            ansv[t] = __bfloat162float(ans[head * 128 + dcol]);
            andv[t] = __bfloat162float(and_[head * 128 + dcol]);
        }
#pragma unroll
        for (int reg = 0; reg < 4; ++reg) {
            float pns = 0.f, pnd = 0.f;
#pragma unroll
            for (int t = 0; t < TB; ++t) {
                pns += acc[t][reg] * ansv[t];
                pnd += acc[t][reg] * andv[t];
            }
#pragma unroll
            for (int o = 1; o < 16; o <<= 1) {
                pns += __shfl_xor(pns, o);
                pnd += __shfl_xor(pnd, o);
            }
            int m = m0 + quad * 4 + reg;
            if (r16 == 0 && m < M) {
                s_ns[m * 3 + head] = pns;
                s_nd[m * 3 + head] = pnd;
            }
        }
    }
}

// ---------------- per-edge softmax numerators (maxless, CSR order) ----------
// Softmax is shift-invariant; scores are O(+-10) so exp never overflows fp32.
__global__ void pedge_kernel(const int* __restrict__ esrc,
                             const int* __restrict__ edst,
                             const float* __restrict__ s_ns,
                             const float* __restrict__ s_nd,
                             float* __restrict__ pedge) {
    int i = blockIdx.x * 256 + threadIdx.x;
    if (i >= N_EDGES) return;
    int s = esrc[i], d = edst[i];
    pedge[i * 3 + 0] = __expf(leaky(s_ns[s * 3 + 0] + s_nd[d * 3 + 0]));
    pedge[i * 3 + 1] = __expf(leaky(s_ns[s * 3 + 1] + s_nd[d * 3 + 1]));
    pedge[i * 3 + 2] = __expf(leaky(s_ns[s * 3 + 2] + s_nd[d * 3 + 2]));
}

// ---------------- aggregate: one WAVE per dst node, pure gather loop --------
__global__ __launch_bounds__(256) void agg_kernel(
    const unsigned* __restrict__ h2, const int* __restrict__ rp,
    const int* __restrict__ esrc, const float* __restrict__ pedge,
    bf16* __restrict__ agg)
{
    const int node = blockIdx.x * 4 + (threadIdx.x >> 6);
    if (node >= N_NODES) return;
    const int lane = threadIdx.x & 63;
    const int beg = rp[node], end = rp[node + 1];
    const int cnt = end - beg;
    unsigned* outp = (unsigned*)(agg + (size_t)node * (HEADS * DIM));
    if (cnt <= 0) {
        outp[lane] = 0u; outp[64 + lane] = 0u; outp[128 + lane] = 0u;
        return;
    }
    float ss0 = 0.f, ss1 = 0.f, ss2 = 0.f;
    float a0 = 0.f, a1 = 0.f, a2 = 0.f, a3 = 0.f, a4 = 0.f, a5 = 0.f;
    const float* pp = pedge + (size_t)beg * 3;
    const int* ep = esrc + beg;
#pragma unroll 4
    for (int j = 0; j < cnt; ++j) {
        int s = ep[j];                    // same addr all lanes -> broadcast
        float p0 = pp[j * 3 + 0];
        float p1 = pp[j * 3 + 1];
        float p2 = pp[j * 3 + 2];
        ss0 += p0; ss1 += p1; ss2 += p2;  // identical in all lanes
        v3u w = *(const v3u*)(h2 + (size_t)s * 192 + lane * 3);
        a0 += p0 * lo2f(w.x); a1 += p0 * hi2f(w.x);
        a2 += p1 * lo2f(w.y); a3 += p1 * hi2f(w.y);
        a4 += p2 * lo2f(w.z); a5 += p2 * hi2f(w.z);
    }
    float i0 = 1.f / ss0, i1 = 1.f / ss1, i2 = 1.f / ss2;
    outp[lane]       = packbf(a0 * i0, a1 * i0);
    outp[64 + lane]  = packbf(a2 * i1, a3 * i1);
    outp[128 + lane] = packbf(a4 * i2, a5 * i2);
}

// ---------------- pooled accumulation w/ inline stats: 8 blocks/graph -------
__global__ __launch_bounds__(256) void pool_acc(
    const bf16* __restrict__ feat, const float* __restrict__ gate,
    const int* __restrict__ gptr, float* __restrict__ out_acc)
{
    const int g = blockIdx.x;
    const int chunk = blockIdx.y;
    const int tid = threadIdx.x;
    const int beg = gptr[g], end = gptr[g + 1];
    if (beg >= end) return;
    __shared__ float red[4];
    // inline per-graph softmax stats (redundant across the 8 chunks; cheap)
    float m = -1e30f;
    for (int i = beg + tid; i < end; i += 256) m = fmaxf(m, gate[i]);
#pragma unroll
    for (int o = 32; o > 0; o >>= 1) m = fmaxf(m, __shfl_xor(m, o));
    if ((tid & 63) == 0) red[tid >> 6] = m;
    __syncthreads();
    m = fmaxf(fmaxf(red[0], red[1]), fmaxf(red[2], red[3]));
    __syncthreads();
    float s = 0.f;
    for (int i = beg + tid; i < end; i += 256) s += __expf(gate[i] - m);
#pragma unroll
    for (int o = 32; o > 0; o >>= 1) s += __shfl_xor(s, o);
    if ((tid & 63) == 0) red[tid >> 6] = s;
    __syncthreads();
    float inv = 1.f / (red[0] + red[1] + red[2] + red[3]);
    // accumulate this chunk's node rows
    const int p = tid >> 7;           // 0..1
    const int c = tid & 127;
    float acc = 0.f;
    for (int i = beg + chunk * 2 + p; i < end; i += 16) {
        float w = __expf(gate[i] - m);
        acc += w * __bfloat162float(feat[(size_t)i * DIM + c]);
    }
    acc *= inv;
    atomicAdd(&out_acc[g * DIM + c], acc);
}

__global__ void writeout_kernel(const float* __restrict__ out_acc,
                                void* __restrict__ out, const int* __restrict__ flag) {
    int i = blockIdx.x * 256 + threadIdx.x;
    if (i < NGRAPH * DIM) {
        float v = out_acc[i] * (1.f / 3.f);
        if ((*flag) > 8) ((float*)out)[i] = v;
        else ((bf16*)out)[i] = __float2bfloat16(v);
    }
}

// ---------------- host launcher ----------------
extern "C" void kernel_launch(void* const* d_in, const int* in_sizes, int n_in,
                              void* d_out, int out_size, void* d_ws, size_t ws_size,
                              hipStream_t stream)
{
    const void* feat_in = d_in[0];
    const int* src = (const int*)d_in[1];
    const int* dst = (const int*)d_in[2];
    const int* gid = (const int*)d_in[3];

    char* base = (char*)d_ws;
    size_t off = 0;
    auto carve = [&](size_t bytes) -> void* {
        void* p = base + off;
        off = (off + bytes + 255) & ~(size_t)255;
        return p;
    };
    // zeroed region: dflag | deg | cursor | out_acc | gateb[3] -> ONE memset
    size_t zbytes = 256 + sizeof(int) * 2 * N_NODES + sizeof(float) * NGRAPH * DIM
                  + sizeof(float) * LAYERS * N_NODES;
    char* zreg  = (char*)carve(zbytes);
    int* dflag  = (int*)zreg;
    int* deg    = (int*)(zreg + 256);
    int* cursor = deg + N_NODES;
    float* out_acc = (float*)(cursor + N_NODES);
    float* gateb3  = out_acc + NGRAPH * DIM;
    int* rp     = (int*)carve(sizeof(int) * (N_NODES + 1));
    int* gptr   = (int*)carve(sizeof(int) * (NGRAPH + 1));
    int* esrc   = (int*)carve(sizeof(int) * N_EDGES);
    int* edst   = (int*)carve(sizeof(int) * N_EDGES);
    float* pedge = (float*)carve(sizeof(float) * N_EDGES * 3);
    float* s_ns = (float*)carve(sizeof(float) * N_NODES * HEADS);
    float* s_nd = (float*)carve(sizeof(float) * N_NODES * HEADS);
    bf16* featA = (bf16*)carve(sizeof(bf16) * N_NODES * DIM);
    bf16* featB = (bf16*)carve(sizeof(bf16) * N_NODES * DIM);
    bf16* cfc   = (bf16*)carve(sizeof(bf16) * LAYERS * HEADS * DIM * DIM);
    bf16* cans  = (bf16*)carve(sizeof(bf16) * LAYERS * HEADS * DIM);
    bf16* cand  = (bf16*)carve(sizeof(bf16) * LAYERS * HEADS * DIM);
    bf16* ctw   = (bf16*)carve(sizeof(bf16) * LAYERS * DIM * HEADS * DIM);
    bf16* ctb   = (bf16*)carve(sizeof(bf16) * LAYERS * DIM);
    bf16* cp1w  = (bf16*)carve(sizeof(bf16) * LAYERS * 2 * DIM * DIM);
    bf16* cp1b  = (bf16*)carve(sizeof(bf16) * LAYERS * 2 * DIM);
    bf16* cp2w  = (bf16*)carve(sizeof(bf16) * LAYERS * 2 * DIM);
    bf16* hbuf   = (bf16*)carve(sizeof(bf16) * N_NODES * HEADS * DIM);
    bf16* aggbuf = (bf16*)carve(sizeof(bf16) * N_NODES * HEADS * DIM);

    if (off > ws_size) {
        sentinel_kernel<<<(out_size + 255) / 256, 256, 0, stream>>>(
            (bf16*)d_out, out_size);
        return;
    }

    hipMemsetAsync(zreg, 0, zbytes, stream);
    detect_kernel<<<128, 256, 0, stream>>>(
        (const unsigned short*)feat_in, 32768, dflag);

    CvtArgs ca;
    const int cvt_n[NCVT] = {
        N_NODES * DIM, LAYERS * HEADS * DIM * DIM, LAYERS * HEADS * DIM,
        LAYERS * HEADS * DIM, LAYERS * DIM * HEADS * DIM, LAYERS * DIM,
        LAYERS * 2 * DIM * DIM, LAYERS * 2 * DIM, LAYERS * 2 * DIM };
    bf16* cvt_dst[NCVT] = { featA, cfc, cans, cand, ctw, ctb, cp1w, cp1b, cp2w };
    const int cvt_src_idx[NCVT] = { 0, 4, 5, 6, 7, 8, 9, 10, 11 };
    int total4 = 0;
    for (int s = 0; s < NCVT; ++s) {
        ca.src[s] = d_in[cvt_src_idx[s]];
        ca.dst[s] = cvt_dst[s];
        ca.n[s] = cvt_n[s];
        ca.n4[s] = (cvt_n[s] + 3) / 4;
        total4 += ca.n4[s];
    }
    cvt_all_kernel<<<(total4 + 255) / 256, 256, 0, stream>>>(ca, dflag);

    count_kernel<<<(N_EDGES + 255) / 256, 256, 0, stream>>>(dst, deg, N_EDGES);
    scan_kernel<<<1, 256, 0, stream>>>(deg, rp, N_NODES);
    gptr_kernel<<<1, 128, 0, stream>>>(gid, gptr);
    fill_kernel<<<(N_EDGES + 255) / 256, 256, 0, stream>>>(
        src, dst, rp, cursor, esrc, edst);

    bf16* fin = featA;
    bf16* fout = featB;
    for (int d = 0; d < LAYERS; ++d) {
        float* gateb = gateb3 + (size_t)d * N_NODES;
        // h (head-interleaved) = feat @ fc_w^T + fused scores : [N, 384]
        gemm_mfma<8, 1><<<dim3(313, 3), 256, 0, stream>>>(
            fin, cfc + (size_t)d * HEADS * DIM * DIM, hbuf,
            N_NODES, HEADS * DIM, DIM, nullptr, nullptr, 0,
            cans + (size_t)d * HEADS * DIM, cand + (size_t)d * HEADS * DIM,
            s_ns, s_nd, nullptr, nullptr);
        pedge_kernel<<<(N_EDGES + 255) / 256, 256, 0, stream>>>(
            esrc, edst, s_ns, s_nd, pedge);
        agg_kernel<<<(N_NODES + 3) / 4, 256, 0, stream>>>(
            (const unsigned*)hbuf, rp, esrc, pedge, aggbuf);
        gemm_mfma<4, 0><<<dim3(313, 2), 256, 0, stream>>>(
            aggbuf, ctw + (size_t)d * DIM * HEADS * DIM, fout,
            N_NODES, DIM, HEADS * DIM, ctb + (size_t)d * DIM, fin,
            (d < LAYERS - 1) ? 1 : 0, nullptr, nullptr, nullptr, nullptr,
            nullptr, nullptr);
        // gate: fused layer1+layer2, no h1 materialization (p2b dropped:
        // softmax is shift-invariant)
        gemm_mfma<8, 2><<<dim3(313, 2), 256, 0, stream>>>(
            fout, cp1w + (size_t)d * 2 * DIM * DIM, nullptr,
            N_NODES, 2 * DIM, DIM, cp1b + (size_t)d * 2 * DIM, nullptr, 1,
            nullptr, nullptr, nullptr, nullptr,
            cp2w + (size_t)d * 2 * DIM, gateb);
        pool_acc<<<dim3(NGRAPH, 8), 256, 0, stream>>>(
            fout, gateb, gptr, out_acc);
        bf16* t = fin; fin = fout; fout = t;
    }
    writeout_kernel<<<(NGRAPH * DIM + 255) / 256, 256, 0, stream>>>(
        out_acc, d_out, dflag);
}

// Round 10
// 460.601 us; speedup vs baseline: 3.0092x; 1.1061x over previous
//
#include <hip/hip_runtime.h>
#include <hip/hip_bf16.h>

#define N_NODES 20000
#define N_EDGES 320000
#define DIM 128
#define HEADS 3
#define LAYERS 3
#define NGRAPH 64
#define NEG_SLOPE 0.2f

typedef const __hip_bfloat16* bfp;
typedef __hip_bfloat16 bf16;
typedef short v8s __attribute__((ext_vector_type(8)));
typedef float v4f __attribute__((ext_vector_type(4)));
typedef unsigned v3u __attribute__((ext_vector_type(3)));

#define GLD_LDS(gp, lp) \
    __builtin_amdgcn_global_load_lds( \
        (const __attribute__((address_space(1))) void*)(gp), \
        (__attribute__((address_space(3))) void*)(lp), 16, 0, 0)

__device__ __forceinline__ float b2f(unsigned short u) {
    return __uint_as_float(((unsigned)u) << 16);
}
__device__ __forceinline__ float lo2f(unsigned u) { return __uint_as_float(u << 16); }
__device__ __forceinline__ float hi2f(unsigned u) { return __uint_as_float(u & 0xffff0000u); }
__device__ __forceinline__ float leaky(float z) {
    return z >= 0.f ? z : NEG_SLOPE * z;
}
__device__ __forceinline__ unsigned packbf(float a, float b) {
    bf16 x = __float2bfloat16(a), y = __float2bfloat16(b);
    return (unsigned)*(unsigned short*)&x | ((unsigned)*(unsigned short*)&y << 16);
}

// ---------------- dtype detection (fp32 vs bf16 storage) ----------------
__global__ void detect_kernel(const unsigned short* __restrict__ probe,
                              int nshorts, int* __restrict__ cnt) {
    int i = blockIdx.x * 256 + threadIdx.x;
    if (i < nshorts) {
        int e = (probe[i] >> 7) & 0xFF;
        if (e >= 140) atomicAdd(cnt, 1);
    }
}

// fused conversion of all float inputs into bf16 ws copies (4 elems/thread)
#define NCVT 9
struct CvtArgs {
    const void* src[NCVT];
    bf16* dst[NCVT];
    int n4[NCVT];
    int n[NCVT];
};
__global__ void cvt_all_kernel(CvtArgs args, const int* __restrict__ flag) {
    int i = blockIdx.x * 256 + threadIdx.x;
    int f = (*flag) > 8;
#pragma unroll
    for (int s = 0; s < NCVT; ++s) {
        int ns4 = args.n4[s];
        if (i < ns4) {
            int ns = args.n[s];
            int base = i * 4;
            bf16* dst = args.dst[s];
            if (f) {
                const float* sp = (const float*)args.src[s];
                if (base + 3 < ns) {
                    float4 v = *(const float4*)(sp + base);
                    bf16 o0 = __float2bfloat16(v.x), o1 = __float2bfloat16(v.y);
                    bf16 o2 = __float2bfloat16(v.z), o3 = __float2bfloat16(v.w);
                    ushort4 pk = { *(unsigned short*)&o0, *(unsigned short*)&o1,
                                   *(unsigned short*)&o2, *(unsigned short*)&o3 };
                    *(ushort4*)(dst + base) = pk;
                } else {
                    for (int j = 0; j < 4 && base + j < ns; ++j)
                        dst[base + j] = __float2bfloat16(sp[base + j]);
                }
            } else {
                const bf16* sp = (const bf16*)args.src[s];
                if (base + 3 < ns) {
                    *(ushort4*)(dst + base) = *(const ushort4*)(sp + base);
                } else {
                    for (int j = 0; j < 4 && base + j < ns; ++j)
                        dst[base + j] = sp[base + j];
                }
            }
            return;
        }
        i -= ns4;
    }
}

// ---------------- setup kernels ----------------

__global__ void count_kernel(const int* __restrict__ idx, int* __restrict__ cnt, int n) {
    int i = blockIdx.x * 256 + threadIdx.x;
    if (i < n) atomicAdd(&cnt[idx[i]], 1);
}

__global__ void scan_kernel(const int* __restrict__ cnt, int* __restrict__ ptr, int n) {
    __shared__ int sums[256];
    int tid = threadIdx.x;
    int chunk = (n + 255) / 256;
    int b = tid * chunk;
    int e = min(b + chunk, n);
    int loc = 0;
    for (int i = b; i < e; ++i) loc += cnt[i];
    sums[tid] = loc;
    __syncthreads();
    if (tid == 0) {
        int run = 0;
        for (int j = 0; j < 256; ++j) { int t = sums[j]; sums[j] = run; run += t; }
        ptr[n] = run;
    }
    __syncthreads();
    int run = sums[tid];
    for (int i = b; i < e; ++i) { ptr[i] = run; run += cnt[i]; }
}

__global__ void gptr_kernel(const int* __restrict__ gid, int* __restrict__ gptr) {
    int g = threadIdx.x;
    if (g > NGRAPH) return;
    int lo = 0, hi = N_NODES;
    while (lo < hi) {
        int mid = (lo + hi) >> 1;
        if (gid[mid] < g) lo = mid + 1; else hi = mid;
    }
    gptr[g] = lo;
}

__global__ void fill_kernel(const int* __restrict__ src, const int* __restrict__ dst,
                            const int* __restrict__ rp, int* __restrict__ cursor,
                            int* __restrict__ esrc, int* __restrict__ edst) {
    int e = blockIdx.x * 256 + threadIdx.x;
    if (e < N_EDGES) {
        int d = dst[e];
        int pos = rp[d] + atomicAdd(&cursor[d], 1);
        esrc[pos] = src[e];
        edst[pos] = d;
    }
}

__global__ void sentinel_kernel(bf16* out, int n) {
    int i = blockIdx.x * 256 + threadIdx.x;
    if (i < n) out[i] = __float2bfloat16(2.0f);
}

// ---------------- MFMA GEMM, LDS-staged (m97 pattern) -----------------------
// C[M,N] = A[M,K] * B[N,K]^T, bf16 in, fp32 acc. Block tile 128x128, 4 waves,
// each wave 32 rows x 128 cols. A/B staged to LDS via global_load_lds w=16.
// MODE 0: plain C (+bias/relu/resid)
// MODE 1: head-interleaved C + fused scores (N=384, blockIdx.y == head)
// MODE 2: no C; fused gate layer-2: relu(acc+bias).p2w -> atomicAdd gateb
template <int MODE>
__global__ __launch_bounds__(256) void gemm_mfma(
    const bf16* __restrict__ A, const bf16* __restrict__ B,
    bf16* __restrict__ C, int M, int N, int K,
    const bf16* __restrict__ bias, const bf16* __restrict__ resid,
    int do_relu,
    const bf16* __restrict__ ans, const bf16* __restrict__ and_,
    float* __restrict__ s_ns, float* __restrict__ s_nd,
    const bf16* __restrict__ p2w, float* __restrict__ gateb)
{
    __shared__ short lsA[128 * 32];
    __shared__ short lsB[128 * 32];
    const int tid  = threadIdx.x;
    const int wave = tid >> 6;
    const int lane = tid & 63;
    const int quad = lane >> 4;
    const int r16  = lane & 15;
    const int m0 = blockIdx.x * 128;
    const int n0 = blockIdx.y * 128;
    const short* As = (const short*)A;
    const short* Bs = (const short*)B;

    // staging coordinates for this thread (issue 0 and 1)
    const int eo0 = tid * 8;              // element offset in 128x32 tile
    const int r0 = eo0 >> 5, c0 = eo0 & 31;
    const int eo1 = eo0 + 2048;
    const int r1 = eo1 >> 5, c1 = eo1 & 31;

    v4f acc0[8], acc1[8];
#pragma unroll
    for (int t = 0; t < 8; ++t) {
        acc0[t] = (v4f){0.f, 0.f, 0.f, 0.f};
        acc1[t] = (v4f){0.f, 0.f, 0.f, 0.f};
    }

    for (int k0 = 0; k0 < K; k0 += 32) {
        GLD_LDS(As + (size_t)(m0 + r0) * K + k0 + c0, lsA + eo0);
        GLD_LDS(As + (size_t)(m0 + r1) * K + k0 + c1, lsA + eo1);
        GLD_LDS(Bs + (size_t)(n0 + r0) * K + k0 + c0, lsB + eo0);
        GLD_LDS(Bs + (size_t)(n0 + r1) * K + k0 + c1, lsB + eo1);
        __syncthreads();
        v8s a0 = *(const v8s*)(lsA + (wave * 32 + r16) * 32 + quad * 8);
        v8s a1 = *(const v8s*)(lsA + (wave * 32 + 16 + r16) * 32 + quad * 8);
#pragma unroll
        for (int t = 0; t < 8; ++t) {
            v8s b = *(const v8s*)(lsB + (t * 16 + r16) * 32 + quad * 8);
            acc0[t] = __builtin_amdgcn_mfma_f32_16x16x32_bf16(a0, b, acc0[t], 0, 0, 0);
            acc1[t] = __builtin_amdgcn_mfma_f32_16x16x32_bf16(a1, b, acc1[t], 0, 0, 0);
        }
        __syncthreads();
    }

    const int mb = m0 + wave * 32;   // this wave's 32-row base

    if (MODE == 2) {
        float pwv[8], bbv[8];
#pragma unroll
        for (int t = 0; t < 8; ++t) {
            int n = n0 + t * 16 + r16;
            pwv[t] = __bfloat162float(p2w[n]);
            bbv[t] = __bfloat162float(bias[n]);
        }
#pragma unroll
        for (int mt = 0; mt < 2; ++mt) {
#pragma unroll
            for (int reg = 0; reg < 4; ++reg) {
                float g = 0.f;
#pragma unroll
                for (int t = 0; t < 8; ++t) {
                    float v = (mt == 0 ? acc0[t][reg] : acc1[t][reg]);
                    g += fmaxf(v + bbv[t], 0.f) * pwv[t];
                }
#pragma unroll
                for (int o = 1; o < 16; o <<= 1) g += __shfl_xor(g, o);
                int m = mb + mt * 16 + quad * 4 + reg;
                if (r16 == 0 && m < M) atomicAdd(&gateb[m], g);
            }
        }
        return;
    }

#pragma unroll
    for (int t = 0; t < 8; ++t) {
        const int n = n0 + t * 16 + r16;
        float bb = bias ? __bfloat162float(bias[n]) : 0.f;
#pragma unroll
        for (int mt = 0; mt < 2; ++mt) {
#pragma unroll
            for (int reg = 0; reg < 4; ++reg) {
                const int m = mb + mt * 16 + quad * 4 + reg;
                if (m >= M) continue;
                float v = (mt == 0 ? acc0[t][reg] : acc1[t][reg]);
                if (bias) {
                    v += bb;
                    if (do_relu) v = fmaxf(v, 0.f);
                }
                if (resid) v += __bfloat162float(resid[(size_t)m * N + n]);
                size_t idx;
                if (MODE == 1) {
                    int d = n & 127, head = n >> 7;
                    idx = (size_t)m * N + (size_t)((d >> 1) * 6 + head * 2 + (d & 1));
                } else {
                    idx = (size_t)m * N + n;
                }
                C[idx] = __float2bfloat16(v);
            }
        }
    }

    if (MODE == 1) {
        const int head = blockIdx.y;
        float ansv[8], andv[8];
#pragma unroll
        for (int t = 0; t < 8; ++t) {
            int dcol = t * 16 + r16;
            ansv[t] = __bfloat162float(ans[head * 128 + dcol]);
            andv[t] = __bfloat162float(and_[head * 128 + dcol]);
        }
#pragma unroll
        for (int mt = 0; mt < 2; ++mt) {
#pragma unroll
            for (int reg = 0; reg < 4; ++reg) {
                float pns = 0.f, pnd = 0.f;
#pragma unroll
                for (int t = 0; t < 8; ++t) {
                    float v = (mt == 0 ? acc0[t][reg] : acc1[t][reg]);
                    pns += v * ansv[t];
                    pnd += v * andv[t];
                }
#pragma unroll
                for (int o = 1; o < 16; o <<= 1) {
                    pns += __shfl_xor(pns, o);
                    pnd += __shfl_xor(pnd, o);
                }
                int m = mb + mt * 16 + quad * 4 + reg;
                if (r16 == 0 && m < M) {
                    s_ns[m * 3 + head] = pns;
                    s_nd[m * 3 + head] = pnd;
                }
            }
        }
    }
}

// ---------------- per-edge softmax numerators (maxless, CSR order) ----------
__global__ void pedge_kernel(const int* __restrict__ esrc,
                             const int* __restrict__ edst,
                             const float* __restrict__ s_ns,
                             const float* __restrict__ s_nd,
                             float* __restrict__ pedge) {
    int i = blockIdx.x * 256 + threadIdx.x;
    if (i >= N_EDGES) return;
    int s = esrc[i], d = edst[i];
    pedge[i * 3 + 0] = __expf(leaky(s_ns[s * 3 + 0] + s_nd[d * 3 + 0]));
    pedge[i * 3 + 1] = __expf(leaky(s_ns[s * 3 + 1] + s_nd[d * 3 + 1]));
    pedge[i * 3 + 2] = __expf(leaky(s_ns[s * 3 + 2] + s_nd[d * 3 + 2]));
}

// ---------------- aggregate: one WAVE per dst node, pure gather loop --------
__global__ __launch_bounds__(256) void agg_kernel(
    const unsigned* __restrict__ h2, const int* __restrict__ rp,
    const int* __restrict__ esrc, const float* __restrict__ pedge,
    bf16* __restrict__ agg)
{
    const int node = blockIdx.x * 4 + (threadIdx.x >> 6);
    if (node >= N_NODES) return;
    const int lane = threadIdx.x & 63;
    const int beg = rp[node], end = rp[node + 1];
    const int cnt = end - beg;
    unsigned* outp = (unsigned*)(agg + (size_t)node * (HEADS * DIM));
    if (cnt <= 0) {
        outp[lane] = 0u; outp[64 + lane] = 0u; outp[128 + lane] = 0u;
        return;
    }
    float ss0 = 0.f, ss1 = 0.f, ss2 = 0.f;
    float a0 = 0.f, a1 = 0.f, a2 = 0.f, a3 = 0.f, a4 = 0.f, a5 = 0.f;
    const float* pp = pedge + (size_t)beg * 3;
    const int* ep = esrc + beg;
#pragma unroll 4
    for (int j = 0; j < cnt; ++j) {
        int s = ep[j];
        float p0 = pp[j * 3 + 0];
        float p1 = pp[j * 3 + 1];
        float p2 = pp[j * 3 + 2];
        ss0 += p0; ss1 += p1; ss2 += p2;
        v3u w = *(const v3u*)(h2 + (size_t)s * 192 + lane * 3);
        a0 += p0 * lo2f(w.x); a1 += p0 * hi2f(w.x);
        a2 += p1 * lo2f(w.y); a3 += p1 * hi2f(w.y);
        a4 += p2 * lo2f(w.z); a5 += p2 * hi2f(w.z);
    }
    float i0 = 1.f / ss0, i1 = 1.f / ss1, i2 = 1.f / ss2;
    outp[lane]       = packbf(a0 * i0, a1 * i0);
    outp[64 + lane]  = packbf(a2 * i1, a3 * i1);
    outp[128 + lane] = packbf(a4 * i2, a5 * i2);
}

// ---------------- pooled accumulation w/ inline stats: 8 blocks/graph -------
__global__ __launch_bounds__(256) void pool_acc(
    const bf16* __restrict__ feat, const float* __restrict__ gate,
    const int* __restrict__ gptr, float* __restrict__ out_acc)
{
    const int g = blockIdx.x;
    const int chunk = blockIdx.y;
    const int tid = threadIdx.x;
    const int beg = gptr[g], end = gptr[g + 1];
    if (beg >= end) return;
    __shared__ float red[4];
    float m = -1e30f;
    for (int i = beg + tid; i < end; i += 256) m = fmaxf(m, gate[i]);
#pragma unroll
    for (int o = 32; o > 0; o >>= 1) m = fmaxf(m, __shfl_xor(m, o));
    if ((tid & 63) == 0) red[tid >> 6] = m;
    __syncthreads();
    m = fmaxf(fmaxf(red[0], red[1]), fmaxf(red[2], red[3]));
    __syncthreads();
    float s = 0.f;
    for (int i = beg + tid; i < end; i += 256) s += __expf(gate[i] - m);
#pragma unroll
    for (int o = 32; o > 0; o >>= 1) s += __shfl_xor(s, o);
    if ((tid & 63) == 0) red[tid >> 6] = s;
    __syncthreads();
    float inv = 1.f / (red[0] + red[1] + red[2] + red[3]);
    const int p = tid >> 7;
    const int c = tid & 127;
    float acc = 0.f;
    for (int i = beg + chunk * 2 + p; i < end; i += 16) {
        float w = __expf(gate[i] - m);
        acc += w * __bfloat162float(feat[(size_t)i * DIM + c]);
    }
    acc *= inv;
    atomicAdd(&out_acc[g * DIM + c], acc);
}

__global__ void writeout_kernel(const float* __restrict__ out_acc,
                                void* __restrict__ out, const int* __restrict__ flag) {
    int i = blockIdx.x * 256 + threadIdx.x;
    if (i < NGRAPH * DIM) {
        float v = out_acc[i] * (1.f / 3.f);
        if ((*flag) > 8) ((float*)out)[i] = v;
        else ((bf16*)out)[i] = __float2bfloat16(v);
    }
}

// ---------------- host launcher ----------------
extern "C" void kernel_launch(void* const* d_in, const int* in_sizes, int n_in,
                              void* d_out, int out_size, void* d_ws, size_t ws_size,
                              hipStream_t stream)
{
    const void* feat_in = d_in[0];
    const int* src = (const int*)d_in[1];
    const int* dst = (const int*)d_in[2];
    const int* gid = (const int*)d_in[3];

    char* base = (char*)d_ws;
    size_t off = 0;
    auto carve = [&](size_t bytes) -> void* {
        void* p = base + off;
        off = (off + bytes + 255) & ~(size_t)255;
        return p;
    };
    size_t zbytes = 256 + sizeof(int) * 2 * N_NODES + sizeof(float) * NGRAPH * DIM
                  + sizeof(float) * LAYERS * N_NODES;
    char* zreg  = (char*)carve(zbytes);
    int* dflag  = (int*)zreg;
    int* deg    = (int*)(zreg + 256);
    int* cursor = deg + N_NODES;
    float* out_acc = (float*)(cursor + N_NODES);
    float* gateb3  = out_acc + NGRAPH * DIM;
    int* rp     = (int*)carve(sizeof(int) * (N_NODES + 1));
    int* gptr   = (int*)carve(sizeof(int) * (NGRAPH + 1));
    int* esrc   = (int*)carve(sizeof(int) * N_EDGES);
    int* edst   = (int*)carve(sizeof(int) * N_EDGES);
    float* pedge = (float*)carve(sizeof(float) * N_EDGES * 3);
    float* s_ns = (float*)carve(sizeof(float) * N_NODES * HEADS);
    float* s_nd = (float*)carve(sizeof(float) * N_NODES * HEADS);
    bf16* featA = (bf16*)carve(sizeof(bf16) * N_NODES * DIM);
    bf16* featB = (bf16*)carve(sizeof(bf16) * N_NODES * DIM);
    bf16* cfc   = (bf16*)carve(sizeof(bf16) * LAYERS * HEADS * DIM * DIM);
    bf16* cans  = (bf16*)carve(sizeof(bf16) * LAYERS * HEADS * DIM);
    bf16* cand  = (bf16*)carve(sizeof(bf16) * LAYERS * HEADS * DIM);
    bf16* ctw   = (bf16*)carve(sizeof(bf16) * LAYERS * DIM * HEADS * DIM);
    bf16* ctb   = (bf16*)carve(sizeof(bf16) * LAYERS * DIM);
    bf16* cp1w  = (bf16*)carve(sizeof(bf16) * LAYERS * 2 * DIM * DIM);
    bf16* cp1b  = (bf16*)carve(sizeof(bf16) * LAYERS * 2 * DIM);
    bf16* cp2w  = (bf16*)carve(sizeof(bf16) * LAYERS * 2 * DIM);
    bf16* hbuf   = (bf16*)carve(sizeof(bf16) * N_NODES * HEADS * DIM);
    bf16* aggbuf = (bf16*)carve(sizeof(bf16) * N_NODES * HEADS * DIM);
    carve(131072);   // pad: GEMM A-tile tail overreads (96 rows x 384 x 2B)

    if (off > ws_size) {
        sentinel_kernel<<<(out_size + 255) / 256, 256, 0, stream>>>(
            (bf16*)d_out, out_size);
        return;
    }

    hipMemsetAsync(zreg, 0, zbytes, stream);
    detect_kernel<<<128, 256, 0, stream>>>(
        (const unsigned short*)feat_in, 32768, dflag);

    CvtArgs ca;
    const int cvt_n[NCVT] = {
        N_NODES * DIM, LAYERS * HEADS * DIM * DIM, LAYERS * HEADS * DIM,
        LAYERS * HEADS * DIM, LAYERS * DIM * HEADS * DIM, LAYERS * DIM,
        LAYERS * 2 * DIM * DIM, LAYERS * 2 * DIM, LAYERS * 2 * DIM };
    bf16* cvt_dst[NCVT] = { featA, cfc, cans, cand, ctw, ctb, cp1w, cp1b, cp2w };
    const int cvt_src_idx[NCVT] = { 0, 4, 5, 6, 7, 8, 9, 10, 11 };
    int total4 = 0;
    for (int s = 0; s < NCVT; ++s) {
        ca.src[s] = d_in[cvt_src_idx[s]];
        ca.dst[s] = cvt_dst[s];
        ca.n[s] = cvt_n[s];
        ca.n4[s] = (cvt_n[s] + 3) / 4;
        total4 += ca.n4[s];
    }
    cvt_all_kernel<<<(total4 + 255) / 256, 256, 0, stream>>>(ca, dflag);

    count_kernel<<<(N_EDGES + 255) / 256, 256, 0, stream>>>(dst, deg, N_EDGES);
    scan_kernel<<<1, 256, 0, stream>>>(deg, rp, N_NODES);
    gptr_kernel<<<1, 128, 0, stream>>>(gid, gptr);
    fill_kernel<<<(N_EDGES + 255) / 256, 256, 0, stream>>>(
        src, dst, rp, cursor, esrc, edst);

    const int MBLK = (N_NODES + 127) / 128;   // 157
    bf16* fin = featA;
    bf16* fout = featB;
    for (int d = 0; d < LAYERS; ++d) {
        float* gateb = gateb3 + (size_t)d * N_NODES;
        // h (head-interleaved) = feat @ fc_w^T + fused scores : [N, 384]
        gemm_mfma<1><<<dim3(MBLK, 3), 256, 0, stream>>>(
            fin, cfc + (size_t)d * HEADS * DIM * DIM, hbuf,
            N_NODES, HEADS * DIM, DIM, nullptr, nullptr, 0,
            cans + (size_t)d * HEADS * DIM, cand + (size_t)d * HEADS * DIM,
            s_ns, s_nd, nullptr, nullptr);
        pedge_kernel<<<(N_EDGES + 255) / 256, 256, 0, stream>>>(
            esrc, edst, s_ns, s_nd, pedge);
        agg_kernel<<<(N_NODES + 3) / 4, 256, 0, stream>>>(
            (const unsigned*)hbuf, rp, esrc, pedge, aggbuf);
        gemm_mfma<0><<<dim3(MBLK, 1), 256, 0, stream>>>(
            aggbuf, ctw + (size_t)d * DIM * HEADS * DIM, fout,
            N_NODES, DIM, HEADS * DIM, ctb + (size_t)d * DIM, fin,
            (d < LAYERS - 1) ? 1 : 0, nullptr, nullptr, nullptr, nullptr,
            nullptr, nullptr);
        // gate: fused layer1+layer2, no h1 materialization (p2b dropped)
        gemm_mfma<2><<<dim3(MBLK, 2), 256, 0, stream>>>(
            fout, cp1w + (size_t)d * 2 * DIM * DIM, nullptr,
            N_NODES, 2 * DIM, DIM, cp1b + (size_t)d * 2 * DIM, nullptr, 1,
            nullptr, nullptr, nullptr, nullptr,
            cp2w + (size_t)d * 2 * DIM, gateb);
        pool_acc<<<dim3(NGRAPH, 8), 256, 0, stream>>>(
            fout, gateb, gptr, out_acc);
        bf16* t = fin; fin = fout; fout = t;
    }
    writeout_kernel<<<(NGRAPH * DIM + 255) / 256, 256, 0, stream>>>(
        out_acc, d_out, dflag);
}